// Round 8
// baseline (1332.867 us; speedup 1.0000x reference)
//
#include <hip/hip_runtime.h>
#include <hip/hip_bf16.h>
#include <math.h>

#define KNN 20

typedef __attribute__((ext_vector_type(8))) short bf16x8_t;
typedef __attribute__((ext_vector_type(4))) float f32x4_t;

// bf16 split helpers (RNE)
__device__ __forceinline__ unsigned short f2bf(float f) {
    unsigned u = __float_as_uint(f);
    u += 0x7fffu + ((u >> 16) & 1u);
    return (unsigned short)(u >> 16);
}
__device__ __forceinline__ float bf2f(unsigned short h) {
    return __uint_as_float((unsigned)h << 16);
}

// async global->LDS, 16 B per lane; dest = wave-uniform base + lane*16
__device__ __forceinline__ void gload_lds16(const void* g, void* l) {
    auto gp = reinterpret_cast<const __attribute__((address_space(1))) unsigned*>(
        reinterpret_cast<uintptr_t>(g));
    auto lp = reinterpret_cast<__attribute__((address_space(3))) unsigned*>(
        reinterpret_cast<uintptr_t>(l));
    __builtin_amdgcn_global_load_lds(gp, lp, 16, 0, 0);
}

// 64-lane bitonic ascending sort of one float per lane; returns lane-19 value.
// Seeds the top-20 filter threshold: 20th order statistic of any 64-subset
// is >= the full set's 20th -> valid filter (never rejects a final top-20).
__device__ __forceinline__ float seed_tau(float mv, int l) {
#pragma unroll
    for (int k = 2; k <= 64; k <<= 1) {
#pragma unroll
        for (int j = k >> 1; j > 0; j >>= 1) {
            float o = __shfl_xor(mv, j);
            bool keepMin = (((l & j) == 0) == ((l & k) == 0));
            mv = keepMin ? fminf(mv, o) : fmaxf(mv, o);
        }
    }
    return __shfl(mv, 19);
}

// ---------------------------------------------------------------- rowsq
template<int C>
__global__ void rowsq_kernel(const float* __restrict__ x, float* __restrict__ sq, int N) {
    int i = blockIdx.x * blockDim.x + threadIdx.x;
    if (i >= N) return;
    float s = 0.f;
    if constexpr (C == 64) {
        const float4* p = reinterpret_cast<const float4*>(x + (size_t)i * C);
#pragma unroll
        for (int c = 0; c < 16; ++c) {
            float4 v = p[c];
            s += v.x * v.x + v.y * v.y + v.z * v.z + v.w * v.w;
        }
    } else {
#pragma unroll
        for (int c = 0; c < C; ++c) { float v = x[(size_t)i * C + c]; s += v * v; }
    }
    sq[i] = s;
}

// ---------------------------------------------------------------- triple-bf16 split
// fp32 = h + l + m (exact, 3x8 significand bits). Xs[row][0:64)=h, [64:128)=l,
// [128:192)=m  (seg s at offset s*64).
__global__ void xsplit3_kernel(const float* __restrict__ X,
                               unsigned short* __restrict__ Xs, int N) {
    int t = blockIdx.x * 256 + threadIdx.x;
    if (t >= N * 64) return;
    int r = t >> 6, c = t & 63;
    float v = X[t];
    unsigned short h = f2bf(v);
    float r1 = v - bf2f(h);
    unsigned short lo = f2bf(r1);
    float r2 = r1 - bf2f(lo);
    unsigned short mm = f2bf(r2);
    Xs[(size_t)r * 192 + c] = h;
    Xs[(size_t)r * 192 + 64 + c] = lo;
    Xs[(size_t)r * 192 + 128 + c] = mm;
}

// ---------------------------------------------------------------- fused kNN (C=64)
// Grid (4 chunks, N/64 strips). Block 256 = 4 waves; wave w owns rows
// m0+w*16 .. +15. A (64 rows x 3 segs) LDS-resident; B staged per 64-col
// subtile. 6-term split-bf16 MFMA => distances bit-identical to R7's
// dist_mfma. Distances land in a wave-PRIVATE 16x64 LDS buffer (no barrier
// needed write->select). Per-wave register top-20 (lanes 0..19, lex (d,idx)
// == jax.lax.top_k tie-break), tau-seeded per chunk. Emits per-(row,chunk)
// sorted partial top-20; knn_merge4 folds the 4 chunks.
__global__ __launch_bounds__(256) void knn64_fused_kernel(
    const unsigned short* __restrict__ Xs, const float* __restrict__ sq,
    float* __restrict__ pd, int* __restrict__ pi, int N) {
    __shared__ __align__(16) unsigned short As[3 * 64 * 64];  // 24576 B
    __shared__ __align__(16) unsigned short Bs[3 * 64 * 64];  // 24576 B
    __shared__ __align__(16) float Dt[4 * 16 * 64];           // 16384 B
    const int tid = threadIdx.x;
    const int w = tid >> 6, l = tid & 63;
    const int cb = blockIdx.x;            // chunk id 0..3
    const int m0 = blockIdx.y * 64;       // row strip base
    const int CW = N / 4;                 // chunk width (2048)
    const int jb = cb * CW;               // chunk col base
    const int lr = l >> 3;                // staging row-in-group
    const int soct = ((l & 7) ^ lr) * 8;  // swizzled source octet (shorts)
    const int frow = l & 15;
    const int fq = l >> 4;
    const int fsw = frow & 7;
    float* myDt = Dt + w * 1024;

    // stage A once: 3 segs x 8 row-groups = 24 gload-waves over 4 waves
    for (int u = w; u < 24; u += 4) {
        int seg = u >> 3, rg = u & 7;
        gload_lds16(Xs + (size_t)(m0 + rg * 8 + lr) * 192 + seg * 64 + soct,
                    (void*)(As + seg * 4096 + rg * 512));
    }

    float d_st[16], tf[16]; int i_st[16];
#pragma unroll
    for (int r = 0; r < 16; ++r) {
        d_st[r] = INFINITY; i_st[r] = 0x7fffffff; tf[r] = INFINITY;
    }
    float sqm[4];
#pragma unroll
    for (int r = 0; r < 4; ++r) sqm[r] = sq[m0 + w * 16 + fq * 4 + r];

    const int segA[6] = {0, 0, 1, 1, 0, 2};
    const int segB[6] = {0, 1, 0, 1, 2, 0};

#pragma unroll 1
    for (int sub = 0; sub < CW / 64; ++sub) {
        __syncthreads();  // prior MFMA reads of Bs done (also drains A stage)
        for (int u = w; u < 24; u += 4) {
            int seg = u >> 3, rg = u & 7;
            gload_lds16(Xs + (size_t)(jb + sub * 64 + rg * 8 + lr) * 192 + seg * 64 + soct,
                        (void*)(Bs + seg * 4096 + rg * 512));
        }
        __syncthreads();

        f32x4_t acc[4];
#pragma unroll
        for (int tn = 0; tn < 4; ++tn) acc[tn] = (f32x4_t){0.f, 0.f, 0.f, 0.f};
#pragma unroll
        for (int t6 = 0; t6 < 6; ++t6) {
#pragma unroll
            for (int ks = 0; ks < 2; ++ks) {
                const int o = ((ks * 4 + fq) ^ fsw) * 8;
                bf16x8_t af = *reinterpret_cast<const bf16x8_t*>(
                    As + segA[t6] * 4096 + (w * 16 + frow) * 64 + o);
#pragma unroll
                for (int tn = 0; tn < 4; ++tn) {
                    bf16x8_t bfr = *reinterpret_cast<const bf16x8_t*>(
                        Bs + segB[t6] * 4096 + (tn * 16 + frow) * 64 + o);
                    acc[tn] = __builtin_amdgcn_mfma_f32_16x16x32_bf16(
                        af, bfr, acc[tn], 0, 0, 0);
                }
            }
        }
        // distances -> private Dt (C layout: col=l&15, row=(l>>4)*4+reg)
#pragma unroll
        for (int tn = 0; tn < 4; ++tn) {
            int col = tn * 16 + frow;
            int j = jb + sub * 64 + col;
            float sj = sq[j];
#pragma unroll
            for (int r = 0; r < 4; ++r) {
                int m = m0 + w * 16 + fq * 4 + r;
                float val = sqm[r] + sj - 2.f * acc[tn][r];
                if (m == j) val = INFINITY;
                myDt[(fq * 4 + r) * 64 + col] = val;
            }
        }
        // select: 16 rows, wave-private (compiler inserts lgkm wait on Dt)
#pragma unroll
        for (int r16 = 0; r16 < 16; ++r16) {
            float val = myDt[r16 * 64 + l];
            if (sub == 0) tf[r16] = seed_tau(val, l);
            bool q = val <= tf[r16];
            unsigned long long bal = __ballot(q);
            if (!bal) continue;
            float dcur = d_st[r16]; int icur = i_st[r16];
            float d19v = __shfl(dcur, 19); int i19v = __shfl(icur, 19);
            while (bal) {
                int ln = __ffsll(bal) - 1;
                bal &= bal - 1;
                float cv = __shfl(val, ln);
                int cj = jb + sub * 64 + ln;
                if (cv < d19v || (cv == d19v && cj < i19v)) {
                    bool cmp = (dcur < cv) || (dcur == cv && icur < cj);
                    unsigned long long ib = __ballot(cmp) & 0xFFFFFull;
                    int rr = __popcll(ib);
                    float sd2 = __shfl_up(dcur, 1);
                    int si2 = __shfl_up(icur, 1);
                    if (l == rr) { dcur = cv; icur = cj; }
                    else if (l > rr && l < KNN) { dcur = sd2; icur = si2; }
                    d19v = __shfl(dcur, 19); i19v = __shfl(icur, 19);
                    tf[r16] = fminf(tf[r16], d19v);
                }
            }
            d_st[r16] = dcur; i_st[r16] = icur;
        }
    }
    // emit sorted partial top-20 per (row, chunk)
#pragma unroll
    for (int r16 = 0; r16 < 16; ++r16) {
        if (l < KNN) {
            size_t o = ((size_t)(m0 + w * 16 + r16) * 4 + cb) * KNN + l;
            pd[o] = d_st[r16];
            pi[o] = i_st[r16];
        }
    }
}

// ---------------------------------------------------------------- merge 4 chunk-partials
// One thread per row: 4 sorted 20-lists (disjoint candidates) -> global
// top-20 by lex (d, idx) 4-way merge.
__global__ __launch_bounds__(256) void knn_merge4_kernel(
    const float* __restrict__ pd, const int* __restrict__ pi,
    int* __restrict__ nbrs, int N) {
    int r = blockIdx.x * 256 + threadIdx.x;
    if (r >= N) return;
    const float* d0 = pd + (size_t)r * 4 * KNN;
    const int* ix0 = pi + (size_t)r * 4 * KNN;
    int p0 = 0, p1 = 0, p2 = 0, p3 = 0;
    float h0 = d0[0], h1 = d0[KNN], h2 = d0[2 * KNN], h3 = d0[3 * KNN];
    int g0 = ix0[0], g1 = ix0[KNN], g2 = ix0[2 * KNN], g3 = ix0[3 * KNN];
#pragma unroll 1
    for (int k = 0; k < KNN; ++k) {
        bool aLTb = (h0 < h1) || (h0 == h1 && g0 < g1);
        float ha = aLTb ? h0 : h1; int ga = aLTb ? g0 : g1; int ca = aLTb ? 0 : 1;
        bool cLTd = (h2 < h3) || (h2 == h3 && g2 < g3);
        float hc = cLTd ? h2 : h3; int gc = cLTd ? g2 : g3; int cc = cLTd ? 2 : 3;
        bool aLTc = (ha < hc) || (ha == hc && ga < gc);
        int best = aLTc ? ca : cc;
        nbrs[(size_t)r * KNN + k] = aLTc ? ga : gc;
        if (best == 0) {
            ++p0; h0 = (p0 < KNN) ? d0[p0] : INFINITY;
            g0 = (p0 < KNN) ? ix0[p0] : 0x7fffffff;
        } else if (best == 1) {
            ++p1; h1 = (p1 < KNN) ? d0[KNN + p1] : INFINITY;
            g1 = (p1 < KNN) ? ix0[KNN + p1] : 0x7fffffff;
        } else if (best == 2) {
            ++p2; h2 = (p2 < KNN) ? d0[2 * KNN + p2] : INFINITY;
            g2 = (p2 < KNN) ? ix0[2 * KNN + p2] : 0x7fffffff;
        } else {
            ++p3; h3 = (p3 < KNN) ? d0[3 * KNN + p3] : INFINITY;
            g3 = (p3 < KNN) ? ix0[3 * KNN + p3] : 0x7fffffff;
        }
    }
}

// ---------------------------------------------------------------- knn fused (C=3)
__global__ __launch_bounds__(256) void knn3_fused_kernel(
    const float* __restrict__ X, const float* __restrict__ sq,
    int* __restrict__ nbrs, int N) {
    const int tid = threadIdx.x;
    const int w = tid >> 6, l = tid & 63;
    const int p = blockIdx.x * 4 + w;
    const float x0 = X[(size_t)p * 3], x1 = X[(size_t)p * 3 + 1], x2 = X[(size_t)p * 3 + 2];
    const float sp = sq[p];
    float dl = INFINITY; int il = 0x7fffffff;
    float d19 = INFINITY; int i19 = 0x7fffffff;
    float tau = INFINITY, tf = INFINITY;

#pragma unroll 1
    for (int j0 = 0; j0 < N; j0 += 256) {
        const int jl = j0 + 4 * l;
        const float4* xr = reinterpret_cast<const float4*>(X + (size_t)jl * 3);
        float4 r0 = xr[0], r1 = xr[1], r2 = xr[2];
        float4 sj = *reinterpret_cast<const float4*>(sq + jl);
        float v0 = sp + sj.x - 2.f * (x0 * r0.x + x1 * r0.y + x2 * r0.z);
        float v1 = sp + sj.y - 2.f * (x0 * r0.w + x1 * r1.x + x2 * r1.y);
        float v2 = sp + sj.z - 2.f * (x0 * r1.z + x1 * r1.w + x2 * r2.x);
        float v3 = sp + sj.w - 2.f * (x0 * r2.y + x1 * r2.z + x2 * r2.w);
        if (jl + 0 == p) v0 = INFINITY;
        if (jl + 1 == p) v1 = INFINITY;
        if (jl + 2 == p) v2 = INFINITY;
        if (jl + 3 == p) v3 = INFINITY;
        if (j0 == 0) {
            float mv = fminf(fminf(v0, v1), fminf(v2, v3));
            tau = seed_tau(mv, l);
            tf = tau;
        }
        bool q0 = v0 <= tf, q1 = v1 <= tf, q2 = v2 <= tf, q3 = v3 <= tf;
        unsigned long long anyb = __ballot(q0 | q1 | q2 | q3);
        if (!anyb) continue;
#pragma unroll
        for (int qq = 0; qq < 4; ++qq) {
            float vq = (qq == 0) ? v0 : (qq == 1) ? v1 : (qq == 2) ? v2 : v3;
            unsigned long long bal = __ballot((qq == 0) ? q0 : (qq == 1) ? q1 : (qq == 2) ? q2 : q3);
            while (bal) {
                int ln = __ffsll((unsigned long long)bal) - 1;
                bal &= bal - 1;
                float cv = __shfl(vq, ln);
                int cj = j0 + 4 * ln + qq;
                if (cv < d19 || (cv == d19 && cj < i19)) {
                    bool cmp = (dl < cv) || (dl == cv && il < cj);
                    unsigned long long cb = __ballot(cmp) & 0xFFFFFull;
                    int r = __popcll(cb);
                    float sdl = __shfl_up(dl, 1);
                    int sil = __shfl_up(il, 1);
                    if (l == r) { dl = cv; il = cj; }
                    else if (l > r && l < KNN) { dl = sdl; il = sil; }
                    d19 = __shfl(dl, 19); i19 = __shfl(il, 19);
                    tf = fminf(tau, d19);
                }
            }
        }
    }
    if (l < KNN) nbrs[(size_t)p * KNN + l] = il;
}

// ---------------------------------------------------------------- edgeconv (factored, fp32 exact)
template<int C>
__global__ void prep_w_kernel(const float* __restrict__ w, const float* __restrict__ b,
                              float* __restrict__ WW, float* __restrict__ bb) {
    int t = blockIdx.x * blockDim.x + threadIdx.x;
    if (t < 128) bb[t] = (t < 64) ? b[t] : 0.f;
    if (t >= C * 128) return;
    int c = t >> 7, f = t & 127;
    WW[t] = (f < 64) ? (w[c * 64 + f] - w[(C + c) * 64 + f]) : w[(C + c) * 64 + (f - 64)];
}

template<int C, int ROWS>
__global__ __launch_bounds__(128) void ec_gemm_kernel(
    const float* __restrict__ x, const float* __restrict__ WW,
    const float* __restrict__ bb, float* __restrict__ AB, int N) {
    __shared__ float Ws[C * 128];
    __shared__ float xs[ROWS * C];
    const int tid = threadIdx.x;
    const int r0 = blockIdx.x * ROWS;
    for (int idx = tid; idx < C * 32; idx += 128)
        reinterpret_cast<float4*>(Ws)[idx] = reinterpret_cast<const float4*>(WW)[idx];
    for (int idx = tid; idx < ROWS * C / 4; idx += 128)
        reinterpret_cast<float4*>(xs)[idx] =
            reinterpret_cast<const float4*>(x + (size_t)r0 * C)[idx];
    __syncthreads();
    const float bias = bb[tid];
#pragma unroll 1
    for (int r = 0; r < ROWS; ++r) {
        float acc = bias;
#pragma unroll
        for (int c = 0; c < C; ++c) acc = fmaf(xs[r * C + c], Ws[c * 128 + tid], acc);
        AB[(size_t)(r0 + r) * 128 + tid] = acc;
    }
}

__global__ __launch_bounds__(256) void ec_max_kernel(
    const float* __restrict__ AB, const int* __restrict__ nbrs,
    float* __restrict__ out, int N) {
    const int tid = threadIdx.x;
    const int w = tid >> 6, f = tid & 63;
    const int i = blockIdx.x * 4 + w;
    const float a = AB[(size_t)i * 128 + f];
    const int* nb = nbrs + (size_t)i * KNN;
    float m = -3.4e38f;
#pragma unroll
    for (int j = 0; j < KNN; ++j) {
        int n = nb[j];
        m = fmaxf(m, AB[(size_t)n * 128 + 64 + f]);
    }
    out[(size_t)i * 64 + f] = fmaxf(a + m, 0.f);
}

// ---------------------------------------------------------------- concat + split to bf16 hi/lo
__global__ void concat_split_kernel(const float* __restrict__ a, const float* __restrict__ b,
                                    const float* __restrict__ c,
                                    unsigned short* __restrict__ hi, unsigned short* __restrict__ lo,
                                    int N) {
    int t = blockIdx.x * blockDim.x + threadIdx.x;
    if (t >= N * 192) return;
    int r = t / 192, cc = t % 192;
    float v;
    if (cc < 64) v = a[(size_t)r * 64 + cc];
    else if (cc < 128) v = b[(size_t)r * 64 + cc - 64];
    else v = c[(size_t)r * 64 + cc - 128];
    unsigned short h = f2bf(v);
    hi[t] = h;
    lo[t] = f2bf(v - bf2f(h));
}

// ---------------------------------------------------------------- weight split: BT[F][3K]
__global__ void prep_bsplit_kernel(const float* __restrict__ W, unsigned short* __restrict__ BT,
                                   int K, int F) {
    int t = blockIdx.x * 256 + threadIdx.x;
    int K3 = 3 * K;
    if (t >= F * K3) return;
    int n = t / K3, kp = t - n * K3;
    int seg = kp / K;
    int k = kp - seg * K;
    float v = W[(size_t)k * F + n];
    unsigned short h = f2bf(v);
    BT[t] = (seg == 1) ? f2bf(v - bf2f(h)) : h;
}

// ---------------------------------------------------------------- split-bf16 MFMA GEMM
template<int BM, int BN, int SPLIT>
__global__ __launch_bounds__(256) void mfma_gemm_kernel(
    const unsigned short* __restrict__ Ahi, const unsigned short* __restrict__ Alo,
    const unsigned short* __restrict__ BT, const float* __restrict__ bias,
    float* __restrict__ Cf, unsigned short* __restrict__ Chi, unsigned short* __restrict__ Clo,
    int M, int N, int K) {
    constexpr int WR = BM / 64, WC = BN / 64;
    static_assert(WR * WC == 4, "4 waves");
    __shared__ __align__(16) unsigned short As[BM * 64];
    __shared__ __align__(16) unsigned short Bs[BN * 64];
    const int tid = threadIdx.x;
    const int w = tid >> 6, l = tid & 63;
    const int wr = w % WR, wc = w / WR;
    const int m0 = blockIdx.y * BM, n0 = blockIdx.x * BN;
    const int K3 = 3 * K;

    f32x4_t acc[4][4];
#pragma unroll
    for (int a = 0; a < 4; ++a)
#pragma unroll
        for (int b = 0; b < 4; ++b) acc[a][b] = (f32x4_t){0.f, 0.f, 0.f, 0.f};

    const int lr = l >> 3;
    const int swz = ((l & 7) ^ lr) * 8;
    const int frow = l & 15;
    const int fq = l >> 4;
    const int fswz = l & 7;

    for (int kt = 0; kt < K3 / 64; ++kt) {
        const int kk = kt * 64;
        const unsigned short* srcA; int k0;
        if (kk < K)            { srcA = Ahi; k0 = kk; }
        else if (kk < 2 * K)   { srcA = Ahi; k0 = kk - K; }
        else                   { srcA = Alo; k0 = kk - 2 * K; }
#pragma unroll
        for (int t = 0; t < BM / 32; ++t) {
            int row = w * (BM / 4) + t * 8;
            gload_lds16(srcA + (size_t)(m0 + row + lr) * K + k0 + swz,
                        (void*)(As + row * 64));
        }
#pragma unroll
        for (int t = 0; t < BN / 32; ++t) {
            int row = w * (BN / 4) + t * 8;
            gload_lds16(BT + (size_t)(n0 + row + lr) * K3 + kk + swz,
                        (void*)(Bs + row * 64));
        }
        __syncthreads();
#pragma unroll
        for (int ks = 0; ks < 2; ++ks) {
            bf16x8_t af[4], bf[4];
            const int o = (ks * 4 + fq) ^ fswz;
#pragma unroll
            for (int tm = 0; tm < 4; ++tm) {
                int row = wr * 64 + tm * 16 + frow;
                af[tm] = *reinterpret_cast<const bf16x8_t*>(As + row * 64 + o * 8);
            }
#pragma unroll
            for (int tn = 0; tn < 4; ++tn) {
                int row = wc * 64 + tn * 16 + frow;
                bf[tn] = *reinterpret_cast<const bf16x8_t*>(Bs + row * 64 + o * 8);
            }
#pragma unroll
            for (int tm = 0; tm < 4; ++tm)
#pragma unroll
                for (int tn = 0; tn < 4; ++tn)
                    acc[tm][tn] = __builtin_amdgcn_mfma_f32_16x16x32_bf16(
                        af[tm], bf[tn], acc[tm][tn], 0, 0, 0);
        }
        __syncthreads();
    }

#pragma unroll
    for (int tn = 0; tn < 4; ++tn) {
        int col = n0 + wc * 64 + tn * 16 + (l & 15);
        float bv = bias[col];
#pragma unroll
        for (int tm = 0; tm < 4; ++tm) {
#pragma unroll
            for (int r = 0; r < 4; ++r) {
                int row = m0 + wr * 64 + tm * 16 + (l >> 4) * 4 + r;
                float v = fmaxf(acc[tm][tn][r] + bv, 0.f);
                if constexpr (SPLIT) {
                    unsigned short h = f2bf(v);
                    Chi[(size_t)row * N + col] = h;
                    Clo[(size_t)row * N + col] = f2bf(v - bf2f(h));
                } else {
                    Cf[(size_t)row * N + col] = v;
                }
            }
        }
    }
}

// ---------------------------------------------------------------- last layer + log_softmax
__global__ __launch_bounds__(256) void last_layer_kernel(
    const float* __restrict__ A, const float* __restrict__ W,
    const float* __restrict__ b, float* __restrict__ out, int N) {
    constexpr int KD = 128, NC = 13;
    __shared__ float ws[KD * NC];
    __shared__ float bs[NC];
    const int tid = threadIdx.x;
    for (int idx = tid; idx < KD * NC; idx += 256) ws[idx] = W[idx];
    if (tid < NC) bs[tid] = b[tid];
    __syncthreads();
    int r = blockIdx.x * 256 + tid;
    if (r >= N) return;
    float acc[NC];
#pragma unroll
    for (int f = 0; f < NC; ++f) acc[f] = bs[f];
    const float4* row = reinterpret_cast<const float4*>(A + (size_t)r * KD);
#pragma unroll 4
    for (int c4 = 0; c4 < KD / 4; ++c4) {
        float4 v = row[c4];
#pragma unroll
        for (int f = 0; f < NC; ++f) acc[f] += v.x * ws[(c4 * 4 + 0) * NC + f];
#pragma unroll
        for (int f = 0; f < NC; ++f) acc[f] += v.y * ws[(c4 * 4 + 1) * NC + f];
#pragma unroll
        for (int f = 0; f < NC; ++f) acc[f] += v.z * ws[(c4 * 4 + 2) * NC + f];
#pragma unroll
        for (int f = 0; f < NC; ++f) acc[f] += v.w * ws[(c4 * 4 + 3) * NC + f];
    }
    float m = acc[0];
#pragma unroll
    for (int f = 1; f < NC; ++f) m = fmaxf(m, acc[f]);
    float s = 0.f;
#pragma unroll
    for (int f = 0; f < NC; ++f) s += expf(acc[f] - m);
    float ls = logf(s);
#pragma unroll
    for (int f = 0; f < NC; ++f) out[(size_t)r * NC + f] = acc[f] - m - ls;
}

// ---------------------------------------------------------------- launch
extern "C" void kernel_launch(void* const* d_in, const int* in_sizes, int n_in,
                              void* d_out, int out_size, void* d_ws, size_t ws_size,
                              hipStream_t stream) {
    const float* x   = (const float*)d_in[0];
    const float* w1  = (const float*)d_in[1];
    const float* b1  = (const float*)d_in[2];
    const float* w2  = (const float*)d_in[3];
    const float* b2  = (const float*)d_in[4];
    const float* w3  = (const float*)d_in[5];
    const float* b3  = (const float*)d_in[6];
    const float* wl1 = (const float*)d_in[7];
    const float* bl1 = (const float*)d_in[8];
    const float* wm1 = (const float*)d_in[9];
    const float* bm1 = (const float*)d_in[10];
    const float* wm2 = (const float*)d_in[11];
    const float* bm2 = (const float*)d_in[12];
    const float* wm3 = (const float*)d_in[13];
    const float* bm3 = (const float*)d_in[14];
    float* out = (float*)d_out;

    const int N = in_sizes[0] / 3;  // 8192

    float* ws = (float*)d_ws;
    size_t off = 0;
    auto alloc = [&](size_t n) { float* p = ws + off; off += n; return p; };
    float* sq  = alloc(N);
    int*   nbr = (int*)alloc((size_t)N * KNN);
    float* x1  = alloc((size_t)N * 64);
    float* x2  = alloc((size_t)N * 64);
    float* x3  = alloc((size_t)N * 64);
    float* AB  = alloc((size_t)N * 128);
    float* WW  = alloc(64 * 128);
    float* bb  = alloc(128);
    float* pd  = alloc((size_t)N * 4 * KNN);          // chunk partial dists
    int*   pi  = (int*)alloc((size_t)N * 4 * KNN);    // chunk partial idx
    unsigned short* Xs = (unsigned short*)alloc((size_t)N * 192 / 2);       // triple-split [N][192]
    unsigned short* bt1 = (unsigned short*)alloc((size_t)1024 * 576 / 2);   // [1024][576]
    unsigned short* bt2 = (unsigned short*)alloc((size_t)256 * 3072 / 2);   // [256][3072]
    unsigned short* bt3 = (unsigned short*)alloc((size_t)128 * 768 / 2);    // [128][768]
    // head activations
    float* Z = alloc((size_t)N * 1700);
    unsigned short* cat_hi = (unsigned short*)Z;
    unsigned short* cat_lo = cat_hi + (size_t)N * 192;
    unsigned short* a1_hi  = cat_lo + (size_t)N * 192;
    unsigned short* a1_lo  = a1_hi + (size_t)N * 1024;
    unsigned short* a2_hi  = a1_lo + (size_t)N * 1024;
    unsigned short* a2_lo  = a2_hi + (size_t)N * 256;
    float* a3 = (float*)(a2_lo + (size_t)N * 256);

    // ---- stage 1 (C=3): fused dist+select, single dispatch
    rowsq_kernel<3><<<N / 256, 256, 0, stream>>>(x, sq, N);
    knn3_fused_kernel<<<N / 4, 256, 0, stream>>>(x, sq, nbr, N);
    prep_w_kernel<3><<<2, 256, 0, stream>>>(w1, b1, WW, bb);
    ec_gemm_kernel<3, 8><<<N / 8, 128, 0, stream>>>(x, WW, bb, AB, N);
    ec_max_kernel<<<N / 4, 256, 0, stream>>>(AB, nbr, x1, N);
    // ---- stage 2 (C=64): fully fused MFMA dist + in-LDS select
    rowsq_kernel<64><<<N / 256, 256, 0, stream>>>(x1, sq, N);
    xsplit3_kernel<<<(N * 64 + 255) / 256, 256, 0, stream>>>(x1, Xs, N);
    knn64_fused_kernel<<<dim3(4, N / 64), 256, 0, stream>>>(Xs, sq, pd, pi, N);
    knn_merge4_kernel<<<(N + 255) / 256, 256, 0, stream>>>(pd, pi, nbr, N);
    prep_w_kernel<64><<<32, 256, 0, stream>>>(w2, b2, WW, bb);
    ec_gemm_kernel<64, 8><<<N / 8, 128, 0, stream>>>(x1, WW, bb, AB, N);
    ec_max_kernel<<<N / 4, 256, 0, stream>>>(AB, nbr, x2, N);
    // ---- stage 3 (C=64)
    rowsq_kernel<64><<<N / 256, 256, 0, stream>>>(x2, sq, N);
    xsplit3_kernel<<<(N * 64 + 255) / 256, 256, 0, stream>>>(x2, Xs, N);
    knn64_fused_kernel<<<dim3(4, N / 64), 256, 0, stream>>>(Xs, sq, pd, pi, N);
    knn_merge4_kernel<<<(N + 255) / 256, 256, 0, stream>>>(pd, pi, nbr, N);
    prep_w_kernel<64><<<32, 256, 0, stream>>>(w3, b3, WW, bb);
    ec_gemm_kernel<64, 8><<<N / 8, 128, 0, stream>>>(x2, WW, bb, AB, N);
    ec_max_kernel<<<N / 4, 256, 0, stream>>>(AB, nbr, x3, N);
    // ---- MLP head (split-bf16 MFMA)
    prep_bsplit_kernel<<<(1024 * 576 + 255) / 256, 256, 0, stream>>>(wl1, bt1, 192, 1024);
    prep_bsplit_kernel<<<(256 * 3072 + 255) / 256, 256, 0, stream>>>(wm1, bt2, 1024, 256);
    prep_bsplit_kernel<<<(128 * 768 + 255) / 256, 256, 0, stream>>>(wm2, bt3, 256, 128);
    concat_split_kernel<<<(N * 192 + 255) / 256, 256, 0, stream>>>(x1, x2, x3, cat_hi, cat_lo, N);
    mfma_gemm_kernel<128, 128, 1><<<dim3(1024 / 128, N / 128), 256, 0, stream>>>(
        cat_hi, cat_lo, bt1, bl1, nullptr, a1_hi, a1_lo, N, 1024, 192);
    mfma_gemm_kernel<256, 64, 1><<<dim3(256 / 64, N / 256), 256, 0, stream>>>(
        a1_hi, a1_lo, bt2, bm1, nullptr, a2_hi, a2_lo, N, 256, 1024);
    mfma_gemm_kernel<256, 64, 0><<<dim3(128 / 64, N / 256), 256, 0, stream>>>(
        a2_hi, a2_lo, bt3, bm2, a3, nullptr, nullptr, N, 128, 256);
    last_layer_kernel<<<(N + 255) / 256, 256, 0, stream>>>(a3, wm3, bm3, out, N);
}

// Round 9
// 760.659 us; speedup vs baseline: 1.7523x; 1.7523x over previous
//
#include <hip/hip_runtime.h>
#include <hip/hip_bf16.h>
#include <math.h>

#define KNN 20
#define CHSZ 2048   // candidate chunk size for distance matrix

typedef __attribute__((ext_vector_type(8))) short bf16x8_t;
typedef __attribute__((ext_vector_type(4))) float f32x4_t;

// bf16 split helpers (RNE)
__device__ __forceinline__ unsigned short f2bf(float f) {
    unsigned u = __float_as_uint(f);
    u += 0x7fffu + ((u >> 16) & 1u);
    return (unsigned short)(u >> 16);
}
__device__ __forceinline__ float bf2f(unsigned short h) {
    return __uint_as_float((unsigned)h << 16);
}

// async global->LDS, 16 B per lane; dest = wave-uniform base + lane*16
__device__ __forceinline__ void gload_lds16(const void* g, void* l) {
    auto gp = reinterpret_cast<const __attribute__((address_space(1))) unsigned*>(
        reinterpret_cast<uintptr_t>(g));
    auto lp = reinterpret_cast<__attribute__((address_space(3))) unsigned*>(
        reinterpret_cast<uintptr_t>(l));
    __builtin_amdgcn_global_load_lds(gp, lp, 16, 0, 0);
}

// 64-lane bitonic ascending sort of one float per lane; returns lane-19 value.
// Seeds the top-20 filter threshold: 20th order statistic of any 64-subset
// is >= the full set's 20th -> valid filter (never rejects a final top-20).
__device__ __forceinline__ float seed_tau(float mv, int l) {
#pragma unroll
    for (int k = 2; k <= 64; k <<= 1) {
#pragma unroll
        for (int j = k >> 1; j > 0; j >>= 1) {
            float o = __shfl_xor(mv, j);
            bool keepMin = (((l & j) == 0) == ((l & k) == 0));
            mv = keepMin ? fminf(mv, o) : fmaxf(mv, o);
        }
    }
    return __shfl(mv, 19);
}

// ---------------------------------------------------------------- rowsq
template<int C>
__global__ void rowsq_kernel(const float* __restrict__ x, float* __restrict__ sq, int N) {
    int i = blockIdx.x * blockDim.x + threadIdx.x;
    if (i >= N) return;
    float s = 0.f;
    if constexpr (C == 64) {
        const float4* p = reinterpret_cast<const float4*>(x + (size_t)i * C);
#pragma unroll
        for (int c = 0; c < 16; ++c) {
            float4 v = p[c];
            s += v.x * v.x + v.y * v.y + v.z * v.z + v.w * v.w;
        }
    } else {
#pragma unroll
        for (int c = 0; c < C; ++c) { float v = x[(size_t)i * C + c]; s += v * v; }
    }
    sq[i] = s;
}

// ---------------------------------------------------------------- triple-bf16 split
// fp32 = h + l + m (exact, 3x8 significand bits). Xs[row][0:64)=h, [64:128)=l,
// [128:192)=m.
__global__ void xsplit3_kernel(const float* __restrict__ X,
                               unsigned short* __restrict__ Xs, int N) {
    int t = blockIdx.x * 256 + threadIdx.x;
    if (t >= N * 64) return;
    int r = t >> 6, c = t & 63;
    float v = X[t];
    unsigned short h = f2bf(v);
    float r1 = v - bf2f(h);
    unsigned short lo = f2bf(r1);
    float r2 = r1 - bf2f(lo);
    unsigned short mm = f2bf(r2);
    Xs[(size_t)r * 192 + c] = h;
    Xs[(size_t)r * 192 + 64 + c] = lo;
    Xs[(size_t)r * 192 + 128 + c] = mm;
}

// ---------------------------------------------------------------- dist MFMA (C=64)
// D[m][n] = sq[m] + sq[j] - 2*dot via 6-term split-bf16 MFMA (fp32-ulp
// accuracy). 128x128 tile, 2x2 waves, 16x16x32 bf16 MFMA.
__global__ __launch_bounds__(256) void dist_mfma_kernel(
    const unsigned short* __restrict__ Xs, const float* __restrict__ sq,
    float* __restrict__ D, int chunk_base) {
    __shared__ __align__(16) unsigned short As[128 * 64];
    __shared__ __align__(16) unsigned short Bs[128 * 64];
    const int tid = threadIdx.x;
    const int w = tid >> 6, l = tid & 63;
    const int wr = w & 1, wc = w >> 1;
    const int m0 = blockIdx.y * 128;
    const int n0 = blockIdx.x * 128;          // chunk-local
    const int jb = chunk_base + n0;           // global candidate base
    const int lr = l >> 3;
    const int swz = ((l & 7) ^ lr) * 8;
    const int frow = l & 15;
    const int fq = l >> 4;
    const int fswz = l & 7;

    f32x4_t acc[4][4];
#pragma unroll
    for (int a = 0; a < 4; ++a)
#pragma unroll
        for (int b = 0; b < 4; ++b) acc[a][b] = (f32x4_t){0.f, 0.f, 0.f, 0.f};

    const int segA[6] = {0, 0, 64, 64, 0, 128};
    const int segB[6] = {0, 64, 0, 64, 128, 0};

#pragma unroll 1
    for (int t6 = 0; t6 < 6; ++t6) {
        const int sA = segA[t6], sB = segB[t6];
#pragma unroll
        for (int s = 0; s < 4; ++s) {
            int row = w * 32 + s * 8;
            gload_lds16(Xs + (size_t)(m0 + row + lr) * 192 + sA + swz,
                        (void*)(As + row * 64));
        }
#pragma unroll
        for (int s = 0; s < 4; ++s) {
            int row = w * 32 + s * 8;
            gload_lds16(Xs + (size_t)(jb + row + lr) * 192 + sB + swz,
                        (void*)(Bs + row * 64));
        }
        __syncthreads();
#pragma unroll
        for (int ks = 0; ks < 2; ++ks) {
            bf16x8_t af[4], bf[4];
            const int o = (ks * 4 + fq) ^ fswz;
#pragma unroll
            for (int tm = 0; tm < 4; ++tm)
                af[tm] = *reinterpret_cast<const bf16x8_t*>(
                    As + (wr * 64 + tm * 16 + frow) * 64 + o * 8);
#pragma unroll
            for (int tn = 0; tn < 4; ++tn)
                bf[tn] = *reinterpret_cast<const bf16x8_t*>(
                    Bs + (wc * 64 + tn * 16 + frow) * 64 + o * 8);
#pragma unroll
            for (int tm = 0; tm < 4; ++tm)
#pragma unroll
                for (int tn = 0; tn < 4; ++tn)
                    acc[tm][tn] = __builtin_amdgcn_mfma_f32_16x16x32_bf16(
                        af[tm], bf[tn], acc[tm][tn], 0, 0, 0);
        }
        __syncthreads();
    }

    // epilogue: C/D layout col=lane&15, row=(lane>>4)*4+reg
    float sn[4]; int jn[4], nc[4];
#pragma unroll
    for (int tn = 0; tn < 4; ++tn) {
        nc[tn] = wc * 64 + tn * 16 + (l & 15);
        jn[tn] = jb + nc[tn];
        sn[tn] = sq[jn[tn]];
    }
#pragma unroll
    for (int tm = 0; tm < 4; ++tm) {
#pragma unroll
        for (int r = 0; r < 4; ++r) {
            int m = m0 + wr * 64 + tm * 16 + (l >> 4) * 4 + r;
            float sm = sq[m];
#pragma unroll
            for (int tn = 0; tn < 4; ++tn) {
                float val = sm + sn[tn] - 2.f * acc[tm][tn][r];
                if (m == jn[tn]) val = INFINITY;
                D[(size_t)m * CHSZ + n0 + nc[tn]] = val;
            }
        }
    }
}

// ---------------------------------------------------------------- knn select (C=64 path)
// One wave per point; distributed sorted top-20 (lanes 0..19), lex (d,idx)
// order == jax.lax.top_k tie-break. Loads pipelined upfront; threshold
// seeded (first chunk) from tile-0 lane minima, carried across chunks.
__global__ __launch_bounds__(256) void knn_select_kernel(
    const float* __restrict__ D, float* __restrict__ sd, int* __restrict__ si,
    int* __restrict__ nbrs, int chunk_base, int first, int last) {
    const int tid = threadIdx.x;
    const int w = tid >> 6, l = tid & 63;
    const int p = blockIdx.x * 4 + w;

    float dl = INFINITY; int il = 0x7fffffff;
    if (!first && l < KNN) { dl = sd[(size_t)p * KNN + l]; il = si[(size_t)p * KNN + l]; }
    float d19 = __shfl(dl, 19); int i19 = __shfl(il, 19);

    const float4* Drow = reinterpret_cast<const float4*>(D + (size_t)p * CHSZ);
    float4 v[8];
#pragma unroll
    for (int b = 0; b < 8; ++b) v[b] = Drow[b * 64 + l];

    float tau = INFINITY;
    if (first) {
        float mv = fminf(fminf(v[0].x, v[0].y), fminf(v[0].z, v[0].w));
        tau = seed_tau(mv, l);
    }
    float tf = fminf(tau, d19);

#pragma unroll
    for (int b = 0; b < 8; ++b) {
        bool q0 = v[b].x <= tf, q1 = v[b].y <= tf, q2 = v[b].z <= tf, q3 = v[b].w <= tf;
        unsigned long long anyb = __ballot(q0 | q1 | q2 | q3);
        if (!anyb) continue;
#pragma unroll
        for (int qq = 0; qq < 4; ++qq) {
            float vq = (qq == 0) ? v[b].x : (qq == 1) ? v[b].y : (qq == 2) ? v[b].z : v[b].w;
            unsigned long long bal = __ballot((qq == 0) ? q0 : (qq == 1) ? q1 : (qq == 2) ? q2 : q3);
            while (bal) {
                int ln = __ffsll((unsigned long long)bal) - 1;
                bal &= bal - 1;
                float cv = __shfl(vq, ln);
                int cj = chunk_base + b * 256 + 4 * ln + qq;
                if (cv < d19 || (cv == d19 && cj < i19)) {
                    bool cmp = (dl < cv) || (dl == cv && il < cj);
                    unsigned long long cb = __ballot(cmp) & 0xFFFFFull;
                    int r = __popcll(cb);
                    float sdl = __shfl_up(dl, 1);
                    int sil = __shfl_up(il, 1);
                    if (l == r) { dl = cv; il = cj; }
                    else if (l > r && l < KNN) { dl = sdl; il = sil; }
                    d19 = __shfl(dl, 19); i19 = __shfl(il, 19);
                    tf = fminf(tau, d19);
                }
            }
        }
    }
    if (l < KNN) {
        sd[(size_t)p * KNN + l] = dl;
        si[(size_t)p * KNN + l] = il;
        if (last) nbrs[(size_t)p * KNN + l] = il;
    }
}

// ---------------------------------------------------------------- knn fused (C=3), 2 waves/point
// Block = 4 waves = 2 points x 2 half-scans. Each wave scans its half with a
// seeded register top-20; the two sorted 20-lists (disjoint index ranges ->
// strict lex total order) are merged exactly by a 20-lane rank merge in LDS.
__global__ __launch_bounds__(256) void knn3_fused_kernel(
    const float* __restrict__ X, const float* __restrict__ sq,
    int* __restrict__ nbrs, int N) {
    __shared__ float md[2][2][KNN];
    __shared__ int   mi[2][2][KNN];
    const int tid = threadIdx.x;
    const int w = tid >> 6, l = tid & 63;
    const int pw = w >> 1;       // point slot in block
    const int half = w & 1;      // candidate half
    const int p = blockIdx.x * 2 + pw;
    const int jbeg = half * (N / 2), jend = jbeg + N / 2;
    const float x0 = X[(size_t)p * 3], x1 = X[(size_t)p * 3 + 1], x2 = X[(size_t)p * 3 + 2];
    const float sp = sq[p];
    float dl = INFINITY; int il = 0x7fffffff;
    float d19 = INFINITY; int i19 = 0x7fffffff;
    float tau = INFINITY, tf = INFINITY;

#pragma unroll 1
    for (int j0 = jbeg; j0 < jend; j0 += 256) {
        const int jl = j0 + 4 * l;
        const float4* xr = reinterpret_cast<const float4*>(X + (size_t)jl * 3);
        float4 r0 = xr[0], r1 = xr[1], r2 = xr[2];
        float4 sj = *reinterpret_cast<const float4*>(sq + jl);
        float v0 = sp + sj.x - 2.f * (x0 * r0.x + x1 * r0.y + x2 * r0.z);
        float v1 = sp + sj.y - 2.f * (x0 * r0.w + x1 * r1.x + x2 * r1.y);
        float v2 = sp + sj.z - 2.f * (x0 * r1.z + x1 * r1.w + x2 * r2.x);
        float v3 = sp + sj.w - 2.f * (x0 * r2.y + x1 * r2.z + x2 * r2.w);
        if (jl + 0 == p) v0 = INFINITY;
        if (jl + 1 == p) v1 = INFINITY;
        if (jl + 2 == p) v2 = INFINITY;
        if (jl + 3 == p) v3 = INFINITY;
        if (j0 == jbeg) {
            float mv = fminf(fminf(v0, v1), fminf(v2, v3));
            tau = seed_tau(mv, l);
            tf = tau;
        }
        bool q0 = v0 <= tf, q1 = v1 <= tf, q2 = v2 <= tf, q3 = v3 <= tf;
        unsigned long long anyb = __ballot(q0 | q1 | q2 | q3);
        if (!anyb) continue;
#pragma unroll
        for (int qq = 0; qq < 4; ++qq) {
            float vq = (qq == 0) ? v0 : (qq == 1) ? v1 : (qq == 2) ? v2 : v3;
            unsigned long long bal = __ballot((qq == 0) ? q0 : (qq == 1) ? q1 : (qq == 2) ? q2 : q3);
            while (bal) {
                int ln = __ffsll((unsigned long long)bal) - 1;
                bal &= bal - 1;
                float cv = __shfl(vq, ln);
                int cj = j0 + 4 * ln + qq;
                if (cv < d19 || (cv == d19 && cj < i19)) {
                    bool cmp = (dl < cv) || (dl == cv && il < cj);
                    unsigned long long cb = __ballot(cmp) & 0xFFFFFull;
                    int r = __popcll(cb);
                    float sdl = __shfl_up(dl, 1);
                    int sil = __shfl_up(il, 1);
                    if (l == r) { dl = cv; il = cj; }
                    else if (l > r && l < KNN) { dl = sdl; il = sil; }
                    d19 = __shfl(dl, 19); i19 = __shfl(il, 19);
                    tf = fminf(tau, d19);
                }
            }
        }
    }
    if (l < KNN) { md[pw][half][l] = dl; mi[pw][half][l] = il; }
    __syncthreads();
    // exact rank merge: pos(A[l]) = l + #{B < A[l]}, pos(B[l]) = l + #{A < B[l]}
    if (half == 0 && l < KNN) {
        float a = md[pw][0][l]; int ai = mi[pw][0][l];
        float b = md[pw][1][l]; int bi = mi[pw][1][l];
        int cA = 0, cB = 0;
#pragma unroll
        for (int t = 0; t < KNN; ++t) {
            float bv = md[pw][1][t]; int bj = mi[pw][1][t];
            cA += ((bv < a) || (bv == a && bj < ai)) ? 1 : 0;
            float av = md[pw][0][t]; int aj = mi[pw][0][t];
            cB += ((av < b) || (av == b && aj < bi)) ? 1 : 0;
        }
        int pa = l + cA, pb = l + cB;
        if (pa < KNN) nbrs[(size_t)p * KNN + pa] = ai;
        if (pb < KNN) nbrs[(size_t)p * KNN + pb] = bi;
    }
}

// ---------------------------------------------------------------- edgeconv (factored, fp32 exact)
template<int C>
__global__ void prep_w_kernel(const float* __restrict__ w, const float* __restrict__ b,
                              float* __restrict__ WW, float* __restrict__ bb) {
    int t = blockIdx.x * blockDim.x + threadIdx.x;
    if (t < 128) bb[t] = (t < 64) ? b[t] : 0.f;
    if (t >= C * 128) return;
    int c = t >> 7, f = t & 127;
    WW[t] = (f < 64) ? (w[c * 64 + f] - w[(C + c) * 64 + f]) : w[(C + c) * 64 + (f - 64)];
}

template<int C, int ROWS>
__global__ __launch_bounds__(128) void ec_gemm_kernel(
    const float* __restrict__ x, const float* __restrict__ WW,
    const float* __restrict__ bb, float* __restrict__ AB, int N) {
    __shared__ float Ws[C * 128];
    __shared__ float xs[ROWS * C];
    const int tid = threadIdx.x;
    const int r0 = blockIdx.x * ROWS;
    for (int idx = tid; idx < C * 32; idx += 128)
        reinterpret_cast<float4*>(Ws)[idx] = reinterpret_cast<const float4*>(WW)[idx];
    for (int idx = tid; idx < ROWS * C / 4; idx += 128)
        reinterpret_cast<float4*>(xs)[idx] =
            reinterpret_cast<const float4*>(x + (size_t)r0 * C)[idx];
    __syncthreads();
    const float bias = bb[tid];
#pragma unroll 1
    for (int r = 0; r < ROWS; ++r) {
        float acc = bias;
#pragma unroll
        for (int c = 0; c < C; ++c) acc = fmaf(xs[r * C + c], Ws[c * 128 + tid], acc);
        AB[(size_t)(r0 + r) * 128 + tid] = acc;
    }
}

// out + folded concat-split: also emits the bf16 hi/lo slice of cat at col0.
__global__ __launch_bounds__(256) void ec_max_kernel(
    const float* __restrict__ AB, const int* __restrict__ nbrs,
    float* __restrict__ out,
    unsigned short* __restrict__ cat_hi, unsigned short* __restrict__ cat_lo,
    int col0, int N) {
    const int tid = threadIdx.x;
    const int w = tid >> 6, f = tid & 63;
    const int i = blockIdx.x * 4 + w;
    const float a = AB[(size_t)i * 128 + f];
    const int* nb = nbrs + (size_t)i * KNN;
    float m = -3.4e38f;
#pragma unroll
    for (int j = 0; j < KNN; ++j) {
        int n = nb[j];
        m = fmaxf(m, AB[(size_t)n * 128 + 64 + f]);
    }
    float v = fmaxf(a + m, 0.f);
    out[(size_t)i * 64 + f] = v;
    unsigned short h = f2bf(v);
    cat_hi[(size_t)i * 192 + col0 + f] = h;
    cat_lo[(size_t)i * 192 + col0 + f] = f2bf(v - bf2f(h));
}

// ---------------------------------------------------------------- weight split: BT[F][3K]
__global__ void prep_bsplit_kernel(const float* __restrict__ W, unsigned short* __restrict__ BT,
                                   int K, int F) {
    int t = blockIdx.x * 256 + threadIdx.x;
    int K3 = 3 * K;
    if (t >= F * K3) return;
    int n = t / K3, kp = t - n * K3;
    int seg = kp / K;
    int k = kp - seg * K;
    float v = W[(size_t)k * F + n];
    unsigned short h = f2bf(v);
    BT[t] = (seg == 1) ? f2bf(v - bf2f(h)) : h;
}

// ---------------------------------------------------------------- split-bf16 MFMA GEMM
template<int BM, int BN, int SPLIT>
__global__ __launch_bounds__(256) void mfma_gemm_kernel(
    const unsigned short* __restrict__ Ahi, const unsigned short* __restrict__ Alo,
    const unsigned short* __restrict__ BT, const float* __restrict__ bias,
    float* __restrict__ Cf, unsigned short* __restrict__ Chi, unsigned short* __restrict__ Clo,
    int M, int N, int K) {
    constexpr int WR = BM / 64, WC = BN / 64;
    static_assert(WR * WC == 4, "4 waves");
    __shared__ __align__(16) unsigned short As[BM * 64];
    __shared__ __align__(16) unsigned short Bs[BN * 64];
    const int tid = threadIdx.x;
    const int w = tid >> 6, l = tid & 63;
    const int wr = w % WR, wc = w / WR;
    const int m0 = blockIdx.y * BM, n0 = blockIdx.x * BN;
    const int K3 = 3 * K;

    f32x4_t acc[4][4];
#pragma unroll
    for (int a = 0; a < 4; ++a)
#pragma unroll
        for (int b = 0; b < 4; ++b) acc[a][b] = (f32x4_t){0.f, 0.f, 0.f, 0.f};

    const int lr = l >> 3;
    const int swz = ((l & 7) ^ lr) * 8;
    const int frow = l & 15;
    const int fq = l >> 4;
    const int fswz = l & 7;

    for (int kt = 0; kt < K3 / 64; ++kt) {
        const int kk = kt * 64;
        const unsigned short* srcA; int k0;
        if (kk < K)            { srcA = Ahi; k0 = kk; }
        else if (kk < 2 * K)   { srcA = Ahi; k0 = kk - K; }
        else                   { srcA = Alo; k0 = kk - 2 * K; }
#pragma unroll
        for (int t = 0; t < BM / 32; ++t) {
            int row = w * (BM / 4) + t * 8;
            gload_lds16(srcA + (size_t)(m0 + row + lr) * K + k0 + swz,
                        (void*)(As + row * 64));
        }
#pragma unroll
        for (int t = 0; t < BN / 32; ++t) {
            int row = w * (BN / 4) + t * 8;
            gload_lds16(BT + (size_t)(n0 + row + lr) * K3 + kk + swz,
                        (void*)(Bs + row * 64));
        }
        __syncthreads();
#pragma unroll
        for (int ks = 0; ks < 2; ++ks) {
            bf16x8_t af[4], bf[4];
            const int o = (ks * 4 + fq) ^ fswz;
#pragma unroll
            for (int tm = 0; tm < 4; ++tm) {
                int row = wr * 64 + tm * 16 + frow;
                af[tm] = *reinterpret_cast<const bf16x8_t*>(As + row * 64 + o * 8);
            }
#pragma unroll
            for (int tn = 0; tn < 4; ++tn) {
                int row = wc * 64 + tn * 16 + frow;
                bf[tn] = *reinterpret_cast<const bf16x8_t*>(Bs + row * 64 + o * 8);
            }
#pragma unroll
            for (int tm = 0; tm < 4; ++tm)
#pragma unroll
                for (int tn = 0; tn < 4; ++tn)
                    acc[tm][tn] = __builtin_amdgcn_mfma_f32_16x16x32_bf16(
                        af[tm], bf[tn], acc[tm][tn], 0, 0, 0);
        }
        __syncthreads();
    }

#pragma unroll
    for (int tn = 0; tn < 4; ++tn) {
        int col = n0 + wc * 64 + tn * 16 + (l & 15);
        float bv = bias[col];
#pragma unroll
        for (int tm = 0; tm < 4; ++tm) {
#pragma unroll
            for (int r = 0; r < 4; ++r) {
                int row = m0 + wr * 64 + tm * 16 + (l >> 4) * 4 + r;
                float v = fmaxf(acc[tm][tn][r] + bv, 0.f);
                if constexpr (SPLIT) {
                    unsigned short h = f2bf(v);
                    Chi[(size_t)row * N + col] = h;
                    Clo[(size_t)row * N + col] = f2bf(v - bf2f(h));
                } else {
                    Cf[(size_t)row * N + col] = v;
                }
            }
        }
    }
}

// ---------------------------------------------------------------- last layer + log_softmax
__global__ __launch_bounds__(256) void last_layer_kernel(
    const float* __restrict__ A, const float* __restrict__ W,
    const float* __restrict__ b, float* __restrict__ out, int N) {
    constexpr int KD = 128, NC = 13;
    __shared__ float ws[KD * NC];
    __shared__ float bs[NC];
    const int tid = threadIdx.x;
    for (int idx = tid; idx < KD * NC; idx += 256) ws[idx] = W[idx];
    if (tid < NC) bs[tid] = b[tid];
    __syncthreads();
    int r = blockIdx.x * 256 + tid;
    if (r >= N) return;
    float acc[NC];
#pragma unroll
    for (int f = 0; f < NC; ++f) acc[f] = bs[f];
    const float4* row = reinterpret_cast<const float4*>(A + (size_t)r * KD);
#pragma unroll 4
    for (int c4 = 0; c4 < KD / 4; ++c4) {
        float4 v = row[c4];
#pragma unroll
        for (int f = 0; f < NC; ++f) acc[f] += v.x * ws[(c4 * 4 + 0) * NC + f];
#pragma unroll
        for (int f = 0; f < NC; ++f) acc[f] += v.y * ws[(c4 * 4 + 1) * NC + f];
#pragma unroll
        for (int f = 0; f < NC; ++f) acc[f] += v.z * ws[(c4 * 4 + 2) * NC + f];
#pragma unroll
        for (int f = 0; f < NC; ++f) acc[f] += v.w * ws[(c4 * 4 + 3) * NC + f];
    }
    float m = acc[0];
#pragma unroll
    for (int f = 1; f < NC; ++f) m = fmaxf(m, acc[f]);
    float s = 0.f;
#pragma unroll
    for (int f = 0; f < NC; ++f) s += expf(acc[f] - m);
    float ls = logf(s);
#pragma unroll
    for (int f = 0; f < NC; ++f) out[(size_t)r * NC + f] = acc[f] - m - ls;
}

// ---------------------------------------------------------------- launch
extern "C" void kernel_launch(void* const* d_in, const int* in_sizes, int n_in,
                              void* d_out, int out_size, void* d_ws, size_t ws_size,
                              hipStream_t stream) {
    const float* x   = (const float*)d_in[0];
    const float* w1  = (const float*)d_in[1];
    const float* b1  = (const float*)d_in[2];
    const float* w2  = (const float*)d_in[3];
    const float* b2  = (const float*)d_in[4];
    const float* w3  = (const float*)d_in[5];
    const float* b3  = (const float*)d_in[6];
    const float* wl1 = (const float*)d_in[7];
    const float* bl1 = (const float*)d_in[8];
    const float* wm1 = (const float*)d_in[9];
    const float* bm1 = (const float*)d_in[10];
    const float* wm2 = (const float*)d_in[11];
    const float* bm2 = (const float*)d_in[12];
    const float* wm3 = (const float*)d_in[13];
    const float* bm3 = (const float*)d_in[14];
    float* out = (float*)d_out;

    const int N = in_sizes[0] / 3;  // 8192
    const int NCH = N / CHSZ;       // 4 chunks

    float* ws = (float*)d_ws;
    size_t off = 0;
    auto alloc = [&](size_t n) { float* p = ws + off; off += n; return p; };
    float* sq  = alloc(N);
    int*   nbr = (int*)alloc((size_t)N * KNN);
    float* x1  = alloc((size_t)N * 64);
    float* x2  = alloc((size_t)N * 64);
    float* x3  = alloc((size_t)N * 64);
    float* AB  = alloc((size_t)N * 128);
    float* WW  = alloc(64 * 128);
    float* bb  = alloc(128);
    float* sd  = alloc((size_t)N * KNN);
    int*   si  = (int*)alloc((size_t)N * KNN);
    unsigned short* Xs = (unsigned short*)alloc((size_t)N * 192 / 2);       // triple-split [N][192]
    unsigned short* bt1 = (unsigned short*)alloc((size_t)1024 * 576 / 2);   // [1024][576]
    unsigned short* bt2 = (unsigned short*)alloc((size_t)256 * 3072 / 2);   // [256][3072]
    unsigned short* bt3 = (unsigned short*)alloc((size_t)128 * 768 / 2);    // [128][768]
    // cat lives OUTSIDE the D union (ec_max writes it before/while D is live)
    unsigned short* cat_hi = (unsigned short*)alloc((size_t)N * 192 / 2);
    unsigned short* cat_lo = (unsigned short*)alloc((size_t)N * 192 / 2);
    // union region: D chunk (knn phase) vs head activations (head phase)
    size_t dsz = (size_t)N * CHSZ;  // 16.8M floats > head usage (11.5M)
    float* Z = alloc(dsz);
    float* D = Z;
    unsigned short* a1_hi  = (unsigned short*)Z;
    unsigned short* a1_lo  = a1_hi + (size_t)N * 1024;
    unsigned short* a2_hi  = a1_lo + (size_t)N * 1024;
    unsigned short* a2_lo  = a2_hi + (size_t)N * 256;
    float* a3 = (float*)(a2_lo + (size_t)N * 256);

    // ---- stage 1 (C=3): fused dist+select, 2 waves/point
    rowsq_kernel<3><<<N / 256, 256, 0, stream>>>(x, sq, N);
    knn3_fused_kernel<<<N / 2, 256, 0, stream>>>(x, sq, nbr, N);
    prep_w_kernel<3><<<2, 256, 0, stream>>>(w1, b1, WW, bb);
    ec_gemm_kernel<3, 8><<<N / 8, 128, 0, stream>>>(x, WW, bb, AB, N);
    ec_max_kernel<<<N / 4, 256, 0, stream>>>(AB, nbr, x1, cat_hi, cat_lo, 0, N);
    // ---- stage 2 (C=64): MFMA distance via exact triple-bf16 split
    rowsq_kernel<64><<<N / 256, 256, 0, stream>>>(x1, sq, N);
    xsplit3_kernel<<<(N * 64 + 255) / 256, 256, 0, stream>>>(x1, Xs, N);
    for (int c = 0; c < NCH; ++c) {
        dist_mfma_kernel<<<dim3(CHSZ / 128, N / 128), 256, 0, stream>>>(Xs, sq, D, c * CHSZ);
        knn_select_kernel<<<N / 4, 256, 0, stream>>>(D, sd, si, nbr, c * CHSZ, c == 0, c == NCH - 1);
    }
    prep_w_kernel<64><<<32, 256, 0, stream>>>(w2, b2, WW, bb);
    ec_gemm_kernel<64, 8><<<N / 8, 128, 0, stream>>>(x1, WW, bb, AB, N);
    ec_max_kernel<<<N / 4, 256, 0, stream>>>(AB, nbr, x2, cat_hi, cat_lo, 64, N);
    // ---- stage 3 (C=64)
    rowsq_kernel<64><<<N / 256, 256, 0, stream>>>(x2, sq, N);
    xsplit3_kernel<<<(N * 64 + 255) / 256, 256, 0, stream>>>(x2, Xs, N);
    for (int c = 0; c < NCH; ++c) {
        dist_mfma_kernel<<<dim3(CHSZ / 128, N / 128), 256, 0, stream>>>(Xs, sq, D, c * CHSZ);
        knn_select_kernel<<<N / 4, 256, 0, stream>>>(D, sd, si, nbr, c * CHSZ, c == 0, c == NCH - 1);
    }
    prep_w_kernel<64><<<32, 256, 0, stream>>>(w3, b3, WW, bb);
    ec_gemm_kernel<64, 8><<<N / 8, 128, 0, stream>>>(x2, WW, bb, AB, N);
    ec_max_kernel<<<N / 4, 256, 0, stream>>>(AB, nbr, x3, cat_hi, cat_lo, 128, N);
    // ---- MLP head (split-bf16 MFMA)
    prep_bsplit_kernel<<<(1024 * 576 + 255) / 256, 256, 0, stream>>>(wl1, bt1, 192, 1024);
    prep_bsplit_kernel<<<(256 * 3072 + 255) / 256, 256, 0, stream>>>(wm1, bt2, 1024, 256);
    prep_bsplit_kernel<<<(128 * 768 + 255) / 256, 256, 0, stream>>>(wm2, bt3, 256, 128);
    mfma_gemm_kernel<128, 128, 1><<<dim3(1024 / 128, N / 128), 256, 0, stream>>>(
        cat_hi, cat_lo, bt1, bl1, nullptr, a1_hi, a1_lo, N, 1024, 192);
    mfma_gemm_kernel<256, 64, 1><<<dim3(256 / 64, N / 256), 256, 0, stream>>>(
        a1_hi, a1_lo, bt2, bm1, nullptr, a2_hi, a2_lo, N, 256, 1024);
    mfma_gemm_kernel<256, 64, 0><<<dim3(128 / 64, N / 256), 256, 0, stream>>>(
        a2_hi, a2_lo, bt3, bm2, a3, nullptr, nullptr, N, 128, 256);
    last_layer_kernel<<<(N + 255) / 256, 256, 0, stream>>>(a3, wm3, bm3, out, N);
}

// Round 10
// 751.971 us; speedup vs baseline: 1.7725x; 1.0116x over previous
//
#include <hip/hip_runtime.h>
#include <hip/hip_bf16.h>
#include <math.h>

#define KNN 20
#define CHSZ 2048   // candidate chunk size for distance matrix

typedef __attribute__((ext_vector_type(8))) short bf16x8_t;
typedef __attribute__((ext_vector_type(4))) float f32x4_t;

// bf16 split helpers (RNE)
__device__ __forceinline__ unsigned short f2bf(float f) {
    unsigned u = __float_as_uint(f);
    u += 0x7fffu + ((u >> 16) & 1u);
    return (unsigned short)(u >> 16);
}
__device__ __forceinline__ float bf2f(unsigned short h) {
    return __uint_as_float((unsigned)h << 16);
}

// async global->LDS, 16 B per lane; dest = wave-uniform base + lane*16
__device__ __forceinline__ void gload_lds16(const void* g, void* l) {
    auto gp = reinterpret_cast<const __attribute__((address_space(1))) unsigned*>(
        reinterpret_cast<uintptr_t>(g));
    auto lp = reinterpret_cast<__attribute__((address_space(3))) unsigned*>(
        reinterpret_cast<uintptr_t>(l));
    __builtin_amdgcn_global_load_lds(gp, lp, 16, 0, 0);
}

// 64-lane bitonic ascending sort of one float per lane; returns lane-19 value.
// Seeds the top-20 filter threshold: 20th order statistic of any 64-subset
// is >= the full set's 20th -> valid filter (never rejects a final top-20).
__device__ __forceinline__ float seed_tau(float mv, int l) {
#pragma unroll
    for (int k = 2; k <= 64; k <<= 1) {
#pragma unroll
        for (int j = k >> 1; j > 0; j >>= 1) {
            float o = __shfl_xor(mv, j);
            bool keepMin = (((l & j) == 0) == ((l & k) == 0));
            mv = keepMin ? fminf(mv, o) : fmaxf(mv, o);
        }
    }
    return __shfl(mv, 19);
}

// ---------------------------------------------------------------- rowsq
template<int C>
__global__ void rowsq_kernel(const float* __restrict__ x, float* __restrict__ sq, int N) {
    int i = blockIdx.x * blockDim.x + threadIdx.x;
    if (i >= N) return;
    float s = 0.f;
    if constexpr (C == 64) {
        const float4* p = reinterpret_cast<const float4*>(x + (size_t)i * C);
#pragma unroll
        for (int c = 0; c < 16; ++c) {
            float4 v = p[c];
            s += v.x * v.x + v.y * v.y + v.z * v.z + v.w * v.w;
        }
    } else {
#pragma unroll
        for (int c = 0; c < C; ++c) { float v = x[(size_t)i * C + c]; s += v * v; }
    }
    sq[i] = s;
}

// ---------------------------------------------------------------- triple-bf16 split
// fp32 = h + l + m (exact, 3x8 significand bits). Xs[row][0:64)=h, [64:128)=l,
// [128:192)=m.
__global__ void xsplit3_kernel(const float* __restrict__ X,
                               unsigned short* __restrict__ Xs, int N) {
    int t = blockIdx.x * 256 + threadIdx.x;
    if (t >= N * 64) return;
    int r = t >> 6, c = t & 63;
    float v = X[t];
    unsigned short h = f2bf(v);
    float r1 = v - bf2f(h);
    unsigned short lo = f2bf(r1);
    float r2 = r1 - bf2f(lo);
    unsigned short mm = f2bf(r2);
    Xs[(size_t)r * 192 + c] = h;
    Xs[(size_t)r * 192 + 64 + c] = lo;
    Xs[(size_t)r * 192 + 128 + c] = mm;
}

// ---------------------------------------------------------------- dist MFMA (C=64)
// D[m][n] = sq[m] + sq[j] - 2*dot via 6-term split-bf16 MFMA (fp32-ulp
// accuracy). 128x128 tile, 2x2 waves, 16x16x32 bf16 MFMA. Epilogue goes
// through a padded LDS transpose buffer (stride 132 -> conflict-free) so
// global stores are float4 (16 vec-stores/thread vs 64 scalar: store-issue
// was the kernel's real bottleneck, ~27 us/chunk of dword stores).
__global__ __launch_bounds__(256) void dist_mfma_kernel(
    const unsigned short* __restrict__ Xs, const float* __restrict__ sq,
    float* __restrict__ D, int chunk_base) {
    __shared__ __align__(16) float smemf[64 * 132];       // 33792 B
    unsigned short* As = (unsigned short*)smemf;          // [128*64] 16 KB
    unsigned short* Bs = As + 128 * 64;                   // [128*64] 16 KB
    float* T = smemf;                                     // aliases (after sync)
    const int tid = threadIdx.x;
    const int w = tid >> 6, l = tid & 63;
    const int wr = w & 1, wc = w >> 1;
    const int m0 = blockIdx.y * 128;
    const int n0 = blockIdx.x * 128;          // chunk-local
    const int jb = chunk_base + n0;           // global candidate base
    const int lr = l >> 3;
    const int swz = ((l & 7) ^ lr) * 8;
    const int frow = l & 15;
    const int fq = l >> 4;
    const int fswz = l & 7;

    f32x4_t acc[4][4];
#pragma unroll
    for (int a = 0; a < 4; ++a)
#pragma unroll
        for (int b = 0; b < 4; ++b) acc[a][b] = (f32x4_t){0.f, 0.f, 0.f, 0.f};

    const int segA[6] = {0, 0, 64, 64, 0, 128};
    const int segB[6] = {0, 64, 0, 64, 128, 0};

#pragma unroll 1
    for (int t6 = 0; t6 < 6; ++t6) {
        const int sA = segA[t6], sB = segB[t6];
#pragma unroll
        for (int s = 0; s < 4; ++s) {
            int row = w * 32 + s * 8;
            gload_lds16(Xs + (size_t)(m0 + row + lr) * 192 + sA + swz,
                        (void*)(As + row * 64));
        }
#pragma unroll
        for (int s = 0; s < 4; ++s) {
            int row = w * 32 + s * 8;
            gload_lds16(Xs + (size_t)(jb + row + lr) * 192 + sB + swz,
                        (void*)(Bs + row * 64));
        }
        __syncthreads();
#pragma unroll
        for (int ks = 0; ks < 2; ++ks) {
            bf16x8_t af[4], bf[4];
            const int o = (ks * 4 + fq) ^ fswz;
#pragma unroll
            for (int tm = 0; tm < 4; ++tm)
                af[tm] = *reinterpret_cast<const bf16x8_t*>(
                    As + (wr * 64 + tm * 16 + frow) * 64 + o * 8);
#pragma unroll
            for (int tn = 0; tn < 4; ++tn)
                bf[tn] = *reinterpret_cast<const bf16x8_t*>(
                    Bs + (wc * 64 + tn * 16 + frow) * 64 + o * 8);
#pragma unroll
            for (int tm = 0; tm < 4; ++tm)
#pragma unroll
                for (int tn = 0; tn < 4; ++tn)
                    acc[tm][tn] = __builtin_amdgcn_mfma_f32_16x16x32_bf16(
                        af[tm], bf[tn], acc[tm][tn], 0, 0, 0);
        }
        __syncthreads();
    }

    // epilogue: fold sq terms + diag INF into LDS transpose, then float4 store
    float sn[4]; int jn[4], nc[4];
#pragma unroll
    for (int tn = 0; tn < 4; ++tn) {
        nc[tn] = wc * 64 + tn * 16 + (l & 15);
        jn[tn] = jb + nc[tn];
        sn[tn] = sq[jn[tn]];
    }
#pragma unroll 1
    for (int h = 0; h < 2; ++h) {
        __syncthreads();  // h=0: MFMA reads done; h=1: prior T reads done
        if (wr == h) {
#pragma unroll
            for (int tm = 0; tm < 4; ++tm) {
#pragma unroll
                for (int r = 0; r < 4; ++r) {
                    int rl = tm * 16 + fq * 4 + r;
                    int m = m0 + h * 64 + rl;
                    float smv = sq[m];
#pragma unroll
                    for (int tn = 0; tn < 4; ++tn) {
                        float val = smv + sn[tn] - 2.f * acc[tm][tn][r];
                        if (m == jn[tn]) val = INFINITY;
                        T[rl * 132 + nc[tn]] = val;
                    }
                }
            }
        }
        __syncthreads();
#pragma unroll
        for (int u = 0; u < 8; ++u) {
            int idx = u * 256 + tid;              // 0..2047
            int rl = idx >> 5, c4 = idx & 31;
            float4 v4 = *reinterpret_cast<const float4*>(T + rl * 132 + c4 * 4);
            int m = m0 + h * 64 + rl;
            *reinterpret_cast<float4*>(D + (size_t)m * CHSZ + n0 + c4 * 4) = v4;
        }
    }
}

// ---------------------------------------------------------------- knn select (C=64 path)
// One wave per point; distributed sorted top-20 (lanes 0..19), lex (d,idx)
// order == jax.lax.top_k tie-break. Loads pipelined upfront; threshold
// seeded (first chunk) from tile-0 lane minima, carried across chunks.
__global__ __launch_bounds__(256) void knn_select_kernel(
    const float* __restrict__ D, float* __restrict__ sd, int* __restrict__ si,
    int* __restrict__ nbrs, int chunk_base, int first, int last) {
    const int tid = threadIdx.x;
    const int w = tid >> 6, l = tid & 63;
    const int p = blockIdx.x * 4 + w;

    float dl = INFINITY; int il = 0x7fffffff;
    if (!first && l < KNN) { dl = sd[(size_t)p * KNN + l]; il = si[(size_t)p * KNN + l]; }
    float d19 = __shfl(dl, 19); int i19 = __shfl(il, 19);

    const float4* Drow = reinterpret_cast<const float4*>(D + (size_t)p * CHSZ);
    float4 v[8];
#pragma unroll
    for (int b = 0; b < 8; ++b) v[b] = Drow[b * 64 + l];

    float tau = INFINITY;
    if (first) {
        float mv = fminf(fminf(v[0].x, v[0].y), fminf(v[0].z, v[0].w));
        tau = seed_tau(mv, l);
    }
    float tf = fminf(tau, d19);

#pragma unroll
    for (int b = 0; b < 8; ++b) {
        bool q0 = v[b].x <= tf, q1 = v[b].y <= tf, q2 = v[b].z <= tf, q3 = v[b].w <= tf;
        unsigned long long anyb = __ballot(q0 | q1 | q2 | q3);
        if (!anyb) continue;
#pragma unroll
        for (int qq = 0; qq < 4; ++qq) {
            float vq = (qq == 0) ? v[b].x : (qq == 1) ? v[b].y : (qq == 2) ? v[b].z : v[b].w;
            unsigned long long bal = __ballot((qq == 0) ? q0 : (qq == 1) ? q1 : (qq == 2) ? q2 : q3);
            while (bal) {
                int ln = __ffsll((unsigned long long)bal) - 1;
                bal &= bal - 1;
                float cv = __shfl(vq, ln);
                int cj = chunk_base + b * 256 + 4 * ln + qq;
                if (cv < d19 || (cv == d19 && cj < i19)) {
                    bool cmp = (dl < cv) || (dl == cv && il < cj);
                    unsigned long long cb = __ballot(cmp) & 0xFFFFFull;
                    int r = __popcll(cb);
                    float sdl = __shfl_up(dl, 1);
                    int sil = __shfl_up(il, 1);
                    if (l == r) { dl = cv; il = cj; }
                    else if (l > r && l < KNN) { dl = sdl; il = sil; }
                    d19 = __shfl(dl, 19); i19 = __shfl(il, 19);
                    tf = fminf(tau, d19);
                }
            }
        }
    }
    if (l < KNN) {
        sd[(size_t)p * KNN + l] = dl;
        si[(size_t)p * KNN + l] = il;
        if (last) nbrs[(size_t)p * KNN + l] = il;
    }
}

// ---------------------------------------------------------------- knn fused (C=3)
// One wave per point over all candidates (R7 form — single-wave scan keeps
// the strongest global-20th filter; 2-wave split regressed, see R9).
__global__ __launch_bounds__(256) void knn3_fused_kernel(
    const float* __restrict__ X, const float* __restrict__ sq,
    int* __restrict__ nbrs, int N) {
    const int tid = threadIdx.x;
    const int w = tid >> 6, l = tid & 63;
    const int p = blockIdx.x * 4 + w;
    const float x0 = X[(size_t)p * 3], x1 = X[(size_t)p * 3 + 1], x2 = X[(size_t)p * 3 + 2];
    const float sp = sq[p];
    float dl = INFINITY; int il = 0x7fffffff;
    float d19 = INFINITY; int i19 = 0x7fffffff;
    float tau = INFINITY, tf = INFINITY;

#pragma unroll 1
    for (int j0 = 0; j0 < N; j0 += 256) {
        const int jl = j0 + 4 * l;
        const float4* xr = reinterpret_cast<const float4*>(X + (size_t)jl * 3);
        float4 r0 = xr[0], r1 = xr[1], r2 = xr[2];
        float4 sj = *reinterpret_cast<const float4*>(sq + jl);
        float v0 = sp + sj.x - 2.f * (x0 * r0.x + x1 * r0.y + x2 * r0.z);
        float v1 = sp + sj.y - 2.f * (x0 * r0.w + x1 * r1.x + x2 * r1.y);
        float v2 = sp + sj.z - 2.f * (x0 * r1.z + x1 * r1.w + x2 * r2.x);
        float v3 = sp + sj.w - 2.f * (x0 * r2.y + x1 * r2.z + x2 * r2.w);
        if (jl + 0 == p) v0 = INFINITY;
        if (jl + 1 == p) v1 = INFINITY;
        if (jl + 2 == p) v2 = INFINITY;
        if (jl + 3 == p) v3 = INFINITY;
        if (j0 == 0) {
            float mv = fminf(fminf(v0, v1), fminf(v2, v3));
            tau = seed_tau(mv, l);
            tf = tau;
        }
        bool q0 = v0 <= tf, q1 = v1 <= tf, q2 = v2 <= tf, q3 = v3 <= tf;
        unsigned long long anyb = __ballot(q0 | q1 | q2 | q3);
        if (!anyb) continue;
#pragma unroll
        for (int qq = 0; qq < 4; ++qq) {
            float vq = (qq == 0) ? v0 : (qq == 1) ? v1 : (qq == 2) ? v2 : v3;
            unsigned long long bal = __ballot((qq == 0) ? q0 : (qq == 1) ? q1 : (qq == 2) ? q2 : q3);
            while (bal) {
                int ln = __ffsll((unsigned long long)bal) - 1;
                bal &= bal - 1;
                float cv = __shfl(vq, ln);
                int cj = j0 + 4 * ln + qq;
                if (cv < d19 || (cv == d19 && cj < i19)) {
                    bool cmp = (dl < cv) || (dl == cv && il < cj);
                    unsigned long long cb = __ballot(cmp) & 0xFFFFFull;
                    int r = __popcll(cb);
                    float sdl = __shfl_up(dl, 1);
                    int sil = __shfl_up(il, 1);
                    if (l == r) { dl = cv; il = cj; }
                    else if (l > r && l < KNN) { dl = sdl; il = sil; }
                    d19 = __shfl(dl, 19); i19 = __shfl(il, 19);
                    tf = fminf(tau, d19);
                }
            }
        }
    }
    if (l < KNN) nbrs[(size_t)p * KNN + l] = il;
}

// ---------------------------------------------------------------- edgeconv (factored, fp32 exact)
template<int C>
__global__ void prep_w_kernel(const float* __restrict__ w, const float* __restrict__ b,
                              float* __restrict__ WW, float* __restrict__ bb) {
    int t = blockIdx.x * blockDim.x + threadIdx.x;
    if (t < 128) bb[t] = (t < 64) ? b[t] : 0.f;
    if (t >= C * 128) return;
    int c = t >> 7, f = t & 127;
    WW[t] = (f < 64) ? (w[c * 64 + f] - w[(C + c) * 64 + f]) : w[(C + c) * 64 + (f - 64)];
}

template<int C, int ROWS>
__global__ __launch_bounds__(128) void ec_gemm_kernel(
    const float* __restrict__ x, const float* __restrict__ WW,
    const float* __restrict__ bb, float* __restrict__ AB, int N) {
    __shared__ float Ws[C * 128];
    __shared__ float xs[ROWS * C];
    const int tid = threadIdx.x;
    const int r0 = blockIdx.x * ROWS;
    for (int idx = tid; idx < C * 32; idx += 128)
        reinterpret_cast<float4*>(Ws)[idx] = reinterpret_cast<const float4*>(WW)[idx];
    for (int idx = tid; idx < ROWS * C / 4; idx += 128)
        reinterpret_cast<float4*>(xs)[idx] =
            reinterpret_cast<const float4*>(x + (size_t)r0 * C)[idx];
    __syncthreads();
    const float bias = bb[tid];
#pragma unroll 1
    for (int r = 0; r < ROWS; ++r) {
        float acc = bias;
#pragma unroll
        for (int c = 0; c < C; ++c) acc = fmaf(xs[r * C + c], Ws[c * 128 + tid], acc);
        AB[(size_t)(r0 + r) * 128 + tid] = acc;
    }
}

// out + folded concat-split: also emits the bf16 hi/lo slice of cat at col0.
__global__ __launch_bounds__(256) void ec_max_kernel(
    const float* __restrict__ AB, const int* __restrict__ nbrs,
    float* __restrict__ out,
    unsigned short* __restrict__ cat_hi, unsigned short* __restrict__ cat_lo,
    int col0, int N) {
    const int tid = threadIdx.x;
    const int w = tid >> 6, f = tid & 63;
    const int i = blockIdx.x * 4 + w;
    const float a = AB[(size_t)i * 128 + f];
    const int* nb = nbrs + (size_t)i * KNN;
    float m = -3.4e38f;
#pragma unroll
    for (int j = 0; j < KNN; ++j) {
        int n = nb[j];
        m = fmaxf(m, AB[(size_t)n * 128 + 64 + f]);
    }
    float v = fmaxf(a + m, 0.f);
    out[(size_t)i * 64 + f] = v;
    unsigned short h = f2bf(v);
    cat_hi[(size_t)i * 192 + col0 + f] = h;
    cat_lo[(size_t)i * 192 + col0 + f] = f2bf(v - bf2f(h));
}

// ---------------------------------------------------------------- weight split: BT[F][3K]
__global__ void prep_bsplit_kernel(const float* __restrict__ W, unsigned short* __restrict__ BT,
                                   int K, int F) {
    int t = blockIdx.x * 256 + threadIdx.x;
    int K3 = 3 * K;
    if (t >= F * K3) return;
    int n = t / K3, kp = t - n * K3;
    int seg = kp / K;
    int k = kp - seg * K;
    float v = W[(size_t)k * F + n];
    unsigned short h = f2bf(v);
    BT[t] = (seg == 1) ? f2bf(v - bf2f(h)) : h;
}

// ---------------------------------------------------------------- split-bf16 MFMA GEMM
template<int BM, int BN, int SPLIT>
__global__ __launch_bounds__(256) void mfma_gemm_kernel(
    const unsigned short* __restrict__ Ahi, const unsigned short* __restrict__ Alo,
    const unsigned short* __restrict__ BT, const float* __restrict__ bias,
    float* __restrict__ Cf, unsigned short* __restrict__ Chi, unsigned short* __restrict__ Clo,
    int M, int N, int K) {
    constexpr int WR = BM / 64, WC = BN / 64;
    static_assert(WR * WC == 4, "4 waves");
    __shared__ __align__(16) unsigned short As[BM * 64];
    __shared__ __align__(16) unsigned short Bs[BN * 64];
    const int tid = threadIdx.x;
    const int w = tid >> 6, l = tid & 63;
    const int wr = w % WR, wc = w / WR;
    const int m0 = blockIdx.y * BM, n0 = blockIdx.x * BN;
    const int K3 = 3 * K;

    f32x4_t acc[4][4];
#pragma unroll
    for (int a = 0; a < 4; ++a)
#pragma unroll
        for (int b = 0; b < 4; ++b) acc[a][b] = (f32x4_t){0.f, 0.f, 0.f, 0.f};

    const int lr = l >> 3;
    const int swz = ((l & 7) ^ lr) * 8;
    const int frow = l & 15;
    const int fq = l >> 4;
    const int fswz = l & 7;

    for (int kt = 0; kt < K3 / 64; ++kt) {
        const int kk = kt * 64;
        const unsigned short* srcA; int k0;
        if (kk < K)            { srcA = Ahi; k0 = kk; }
        else if (kk < 2 * K)   { srcA = Ahi; k0 = kk - K; }
        else                   { srcA = Alo; k0 = kk - 2 * K; }
#pragma unroll
        for (int t = 0; t < BM / 32; ++t) {
            int row = w * (BM / 4) + t * 8;
            gload_lds16(srcA + (size_t)(m0 + row + lr) * K + k0 + swz,
                        (void*)(As + row * 64));
        }
#pragma unroll
        for (int t = 0; t < BN / 32; ++t) {
            int row = w * (BN / 4) + t * 8;
            gload_lds16(BT + (size_t)(n0 + row + lr) * K3 + kk + swz,
                        (void*)(Bs + row * 64));
        }
        __syncthreads();
#pragma unroll
        for (int ks = 0; ks < 2; ++ks) {
            bf16x8_t af[4], bf[4];
            const int o = (ks * 4 + fq) ^ fswz;
#pragma unroll
            for (int tm = 0; tm < 4; ++tm) {
                int row = wr * 64 + tm * 16 + frow;
                af[tm] = *reinterpret_cast<const bf16x8_t*>(As + row * 64 + o * 8);
            }
#pragma unroll
            for (int tn = 0; tn < 4; ++tn) {
                int row = wc * 64 + tn * 16 + frow;
                bf[tn] = *reinterpret_cast<const bf16x8_t*>(Bs + row * 64 + o * 8);
            }
#pragma unroll
            for (int tm = 0; tm < 4; ++tm)
#pragma unroll
                for (int tn = 0; tn < 4; ++tn)
                    acc[tm][tn] = __builtin_amdgcn_mfma_f32_16x16x32_bf16(
                        af[tm], bf[tn], acc[tm][tn], 0, 0, 0);
        }
        __syncthreads();
    }

#pragma unroll
    for (int tn = 0; tn < 4; ++tn) {
        int col = n0 + wc * 64 + tn * 16 + (l & 15);
        float bv = bias[col];
#pragma unroll
        for (int tm = 0; tm < 4; ++tm) {
#pragma unroll
            for (int r = 0; r < 4; ++r) {
                int row = m0 + wr * 64 + tm * 16 + (l >> 4) * 4 + r;
                float v = fmaxf(acc[tm][tn][r] + bv, 0.f);
                if constexpr (SPLIT) {
                    unsigned short h = f2bf(v);
                    Chi[(size_t)row * N + col] = h;
                    Clo[(size_t)row * N + col] = f2bf(v - bf2f(h));
                } else {
                    Cf[(size_t)row * N + col] = v;
                }
            }
        }
    }
}

// ---------------------------------------------------------------- last layer + log_softmax
__global__ __launch_bounds__(256) void last_layer_kernel(
    const float* __restrict__ A, const float* __restrict__ W,
    const float* __restrict__ b, float* __restrict__ out, int N) {
    constexpr int KD = 128, NC = 13;
    __shared__ float ws[KD * NC];
    __shared__ float bs[NC];
    const int tid = threadIdx.x;
    for (int idx = tid; idx < KD * NC; idx += 256) ws[idx] = W[idx];
    if (tid < NC) bs[tid] = b[tid];
    __syncthreads();
    int r = blockIdx.x * 256 + tid;
    if (r >= N) return;
    float acc[NC];
#pragma unroll
    for (int f = 0; f < NC; ++f) acc[f] = bs[f];
    const float4* row = reinterpret_cast<const float4*>(A + (size_t)r * KD);
#pragma unroll 4
    for (int c4 = 0; c4 < KD / 4; ++c4) {
        float4 v = row[c4];
#pragma unroll
        for (int f = 0; f < NC; ++f) acc[f] += v.x * ws[(c4 * 4 + 0) * NC + f];
#pragma unroll
        for (int f = 0; f < NC; ++f) acc[f] += v.y * ws[(c4 * 4 + 1) * NC + f];
#pragma unroll
        for (int f = 0; f < NC; ++f) acc[f] += v.z * ws[(c4 * 4 + 2) * NC + f];
#pragma unroll
        for (int f = 0; f < NC; ++f) acc[f] += v.w * ws[(c4 * 4 + 3) * NC + f];
    }
    float m = acc[0];
#pragma unroll
    for (int f = 1; f < NC; ++f) m = fmaxf(m, acc[f]);
    float s = 0.f;
#pragma unroll
    for (int f = 0; f < NC; ++f) s += expf(acc[f] - m);
    float ls = logf(s);
#pragma unroll
    for (int f = 0; f < NC; ++f) out[(size_t)r * NC + f] = acc[f] - m - ls;
}

// ---------------------------------------------------------------- launch
extern "C" void kernel_launch(void* const* d_in, const int* in_sizes, int n_in,
                              void* d_out, int out_size, void* d_ws, size_t ws_size,
                              hipStream_t stream) {
    const float* x   = (const float*)d_in[0];
    const float* w1  = (const float*)d_in[1];
    const float* b1  = (const float*)d_in[2];
    const float* w2  = (const float*)d_in[3];
    const float* b2  = (const float*)d_in[4];
    const float* w3  = (const float*)d_in[5];
    const float* b3  = (const float*)d_in[6];
    const float* wl1 = (const float*)d_in[7];
    const float* bl1 = (const float*)d_in[8];
    const float* wm1 = (const float*)d_in[9];
    const float* bm1 = (const float*)d_in[10];
    const float* wm2 = (const float*)d_in[11];
    const float* bm2 = (const float*)d_in[12];
    const float* wm3 = (const float*)d_in[13];
    const float* bm3 = (const float*)d_in[14];
    float* out = (float*)d_out;

    const int N = in_sizes[0] / 3;  // 8192
    const int NCH = N / CHSZ;       // 4 chunks

    float* ws = (float*)d_ws;
    size_t off = 0;
    auto alloc = [&](size_t n) { float* p = ws + off; off += n; return p; };
    float* sq  = alloc(N);
    int*   nbr = (int*)alloc((size_t)N * KNN);
    float* x1  = alloc((size_t)N * 64);
    float* x2  = alloc((size_t)N * 64);
    float* x3  = alloc((size_t)N * 64);
    float* AB  = alloc((size_t)N * 128);
    float* WW  = alloc(64 * 128);
    float* bb  = alloc(128);
    float* sd  = alloc((size_t)N * KNN);
    int*   si  = (int*)alloc((size_t)N * KNN);
    unsigned short* Xs = (unsigned short*)alloc((size_t)N * 192 / 2);       // triple-split [N][192]
    unsigned short* bt1 = (unsigned short*)alloc((size_t)1024 * 576 / 2);   // [1024][576]
    unsigned short* bt2 = (unsigned short*)alloc((size_t)256 * 3072 / 2);   // [256][3072]
    unsigned short* bt3 = (unsigned short*)alloc((size_t)128 * 768 / 2);    // [128][768]
    // cat lives OUTSIDE the D union (ec_max writes it before/while D is live)
    unsigned short* cat_hi = (unsigned short*)alloc((size_t)N * 192 / 2);
    unsigned short* cat_lo = (unsigned short*)alloc((size_t)N * 192 / 2);
    // union region: D chunk (knn phase) vs head activations (head phase)
    size_t dsz = (size_t)N * CHSZ;  // 16.8M floats > head usage (11.5M)
    float* Z = alloc(dsz);
    float* D = Z;
    unsigned short* a1_hi  = (unsigned short*)Z;
    unsigned short* a1_lo  = a1_hi + (size_t)N * 1024;
    unsigned short* a2_hi  = a1_lo + (size_t)N * 1024;
    unsigned short* a2_lo  = a2_hi + (size_t)N * 256;
    float* a3 = (float*)(a2_lo + (size_t)N * 256);

    // ---- stage 1 (C=3): fused dist+select, single dispatch
    rowsq_kernel<3><<<N / 256, 256, 0, stream>>>(x, sq, N);
    knn3_fused_kernel<<<N / 4, 256, 0, stream>>>(x, sq, nbr, N);
    prep_w_kernel<3><<<2, 256, 0, stream>>>(w1, b1, WW, bb);
    ec_gemm_kernel<3, 8><<<N / 8, 128, 0, stream>>>(x, WW, bb, AB, N);
    ec_max_kernel<<<N / 4, 256, 0, stream>>>(AB, nbr, x1, cat_hi, cat_lo, 0, N);
    // ---- stage 2 (C=64): MFMA distance via exact triple-bf16 split
    rowsq_kernel<64><<<N / 256, 256, 0, stream>>>(x1, sq, N);
    xsplit3_kernel<<<(N * 64 + 255) / 256, 256, 0, stream>>>(x1, Xs, N);
    for (int c = 0; c < NCH; ++c) {
        dist_mfma_kernel<<<dim3(CHSZ / 128, N / 128), 256, 0, stream>>>(Xs, sq, D, c * CHSZ);
        knn_select_kernel<<<N / 4, 256, 0, stream>>>(D, sd, si, nbr, c * CHSZ, c == 0, c == NCH - 1);
    }
    prep_w_kernel<64><<<32, 256, 0, stream>>>(w2, b2, WW, bb);
    ec_gemm_kernel<64, 8><<<N / 8, 128, 0, stream>>>(x1, WW, bb, AB, N);
    ec_max_kernel<<<N / 4, 256, 0, stream>>>(AB, nbr, x2, cat_hi, cat_lo, 64, N);
    // ---- stage 3 (C=64)
    rowsq_kernel<64><<<N / 256, 256, 0, stream>>>(x2, sq, N);
    xsplit3_kernel<<<(N * 64 + 255) / 256, 256, 0, stream>>>(x2, Xs, N);
    for (int c = 0; c < NCH; ++c) {
        dist_mfma_kernel<<<dim3(CHSZ / 128, N / 128), 256, 0, stream>>>(Xs, sq, D, c * CHSZ);
        knn_select_kernel<<<N / 4, 256, 0, stream>>>(D, sd, si, nbr, c * CHSZ, c == 0, c == NCH - 1);
    }
    prep_w_kernel<64><<<32, 256, 0, stream>>>(w3, b3, WW, bb);
    ec_gemm_kernel<64, 8><<<N / 8, 128, 0, stream>>>(x2, WW, bb, AB, N);
    ec_max_kernel<<<N / 4, 256, 0, stream>>>(AB, nbr, x3, cat_hi, cat_lo, 128, N);
    // ---- MLP head (split-bf16 MFMA)
    prep_bsplit_kernel<<<(1024 * 576 + 255) / 256, 256, 0, stream>>>(wl1, bt1, 192, 1024);
    prep_bsplit_kernel<<<(256 * 3072 + 255) / 256, 256, 0, stream>>>(wm1, bt2, 1024, 256);
    prep_bsplit_kernel<<<(128 * 768 + 255) / 256, 256, 0, stream>>>(wm2, bt3, 256, 128);
    mfma_gemm_kernel<128, 128, 1><<<dim3(1024 / 128, N / 128), 256, 0, stream>>>(
        cat_hi, cat_lo, bt1, bl1, nullptr, a1_hi, a1_lo, N, 1024, 192);
    mfma_gemm_kernel<256, 64, 1><<<dim3(256 / 64, N / 256), 256, 0, stream>>>(
        a1_hi, a1_lo, bt2, bm1, nullptr, a2_hi, a2_lo, N, 256, 1024);
    mfma_gemm_kernel<256, 64, 0><<<dim3(128 / 64, N / 256), 256, 0, stream>>>(
        a2_hi, a2_lo, bt3, bm2, a3, nullptr, nullptr, N, 128, 256);
    last_layer_kernel<<<(N + 255) / 256, 256, 0, stream>>>(a3, wm3, bm3, out, N);
}

// Round 11
// 738.612 us; speedup vs baseline: 1.8046x; 1.0181x over previous
//
#include <hip/hip_runtime.h>
#include <hip/hip_bf16.h>
#include <math.h>

#define KNN 20
#define CHSZ 2048   // candidate chunk size for distance matrix

typedef __attribute__((ext_vector_type(8))) short bf16x8_t;
typedef __attribute__((ext_vector_type(4))) float f32x4_t;

// bf16 split helpers (RNE)
__device__ __forceinline__ unsigned short f2bf(float f) {
    unsigned u = __float_as_uint(f);
    u += 0x7fffu + ((u >> 16) & 1u);
    return (unsigned short)(u >> 16);
}
__device__ __forceinline__ float bf2f(unsigned short h) {
    return __uint_as_float((unsigned)h << 16);
}

// async global->LDS, 16 B per lane; dest = wave-uniform base + lane*16
__device__ __forceinline__ void gload_lds16(const void* g, void* l) {
    auto gp = reinterpret_cast<const __attribute__((address_space(1))) unsigned*>(
        reinterpret_cast<uintptr_t>(g));
    auto lp = reinterpret_cast<__attribute__((address_space(3))) unsigned*>(
        reinterpret_cast<uintptr_t>(l));
    __builtin_amdgcn_global_load_lds(gp, lp, 16, 0, 0);
}

// 64-lane bitonic ascending sort of one float per lane; returns lane-19 value.
__device__ __forceinline__ float seed_tau(float mv, int l) {
#pragma unroll
    for (int k = 2; k <= 64; k <<= 1) {
#pragma unroll
        for (int j = k >> 1; j > 0; j >>= 1) {
            float o = __shfl_xor(mv, j);
            bool keepMin = (((l & j) == 0) == ((l & k) == 0));
            mv = keepMin ? fminf(mv, o) : fmaxf(mv, o);
        }
    }
    return __shfl(mv, 19);
}

// ---------------------------------------------------------------- rowsq
template<int C>
__global__ void rowsq_kernel(const float* __restrict__ x, float* __restrict__ sq, int N) {
    int i = blockIdx.x * blockDim.x + threadIdx.x;
    if (i >= N) return;
    float s = 0.f;
    if constexpr (C == 64) {
        const float4* p = reinterpret_cast<const float4*>(x + (size_t)i * C);
#pragma unroll
        for (int c = 0; c < 16; ++c) {
            float4 v = p[c];
            s += v.x * v.x + v.y * v.y + v.z * v.z + v.w * v.w;
        }
    } else {
#pragma unroll
        for (int c = 0; c < C; ++c) { float v = x[(size_t)i * C + c]; s += v * v; }
    }
    sq[i] = s;
}

// ---------------------------------------------------------------- triple-bf16 split
// fp32 = h + l + m (exact, 3x8 significand bits). Xs[row][0:64)=h, [64:128)=l,
// [128:192)=m.
__global__ void xsplit3_kernel(const float* __restrict__ X,
                               unsigned short* __restrict__ Xs, int N) {
    int t = blockIdx.x * 256 + threadIdx.x;
    if (t >= N * 64) return;
    int r = t >> 6, c = t & 63;
    float v = X[t];
    unsigned short h = f2bf(v);
    float r1 = v - bf2f(h);
    unsigned short lo = f2bf(r1);
    float r2 = r1 - bf2f(lo);
    unsigned short mm = f2bf(r2);
    Xs[(size_t)r * 192 + c] = h;
    Xs[(size_t)r * 192 + 64 + c] = lo;
    Xs[(size_t)r * 192 + 128 + c] = mm;
}

// ---------------------------------------------------------------- dist MFMA (C=64)
// D[m][n] = sq[m] + sq[j] - 2*dot via 6-term split-bf16 MFMA (fp32-ulp
// accuracy). 128x128 tile, 2x2 waves, 16x16x32 bf16 MFMA. Epilogue: LDS
// transpose (stride 132) -> float4 stores, plus per-(row, 64-col tile)
// minima rmin[m][32] so the select can skip tiles that cannot contain a
// top-20 candidate.
__global__ __launch_bounds__(256) void dist_mfma_kernel(
    const unsigned short* __restrict__ Xs, const float* __restrict__ sq,
    float* __restrict__ D, float* __restrict__ rmin, int chunk_base) {
    __shared__ __align__(16) float smemf[64 * 132];       // 33792 B
    unsigned short* As = (unsigned short*)smemf;          // [128*64] 16 KB
    unsigned short* Bs = As + 128 * 64;                   // [128*64] 16 KB
    float* T = smemf;                                     // aliases (after sync)
    const int tid = threadIdx.x;
    const int w = tid >> 6, l = tid & 63;
    const int wr = w & 1, wc = w >> 1;
    const int m0 = blockIdx.y * 128;
    const int n0 = blockIdx.x * 128;          // chunk-local
    const int jb = chunk_base + n0;           // global candidate base
    const int lr = l >> 3;
    const int swz = ((l & 7) ^ lr) * 8;
    const int frow = l & 15;
    const int fq = l >> 4;
    const int fswz = l & 7;

    f32x4_t acc[4][4];
#pragma unroll
    for (int a = 0; a < 4; ++a)
#pragma unroll
        for (int b = 0; b < 4; ++b) acc[a][b] = (f32x4_t){0.f, 0.f, 0.f, 0.f};

    const int segA[6] = {0, 0, 64, 64, 0, 128};
    const int segB[6] = {0, 64, 0, 64, 128, 0};

#pragma unroll 1
    for (int t6 = 0; t6 < 6; ++t6) {
        const int sA = segA[t6], sB = segB[t6];
#pragma unroll
        for (int s = 0; s < 4; ++s) {
            int row = w * 32 + s * 8;
            gload_lds16(Xs + (size_t)(m0 + row + lr) * 192 + sA + swz,
                        (void*)(As + row * 64));
        }
#pragma unroll
        for (int s = 0; s < 4; ++s) {
            int row = w * 32 + s * 8;
            gload_lds16(Xs + (size_t)(jb + row + lr) * 192 + sB + swz,
                        (void*)(Bs + row * 64));
        }
        __syncthreads();
#pragma unroll
        for (int ks = 0; ks < 2; ++ks) {
            bf16x8_t af[4], bf[4];
            const int o = (ks * 4 + fq) ^ fswz;
#pragma unroll
            for (int tm = 0; tm < 4; ++tm)
                af[tm] = *reinterpret_cast<const bf16x8_t*>(
                    As + (wr * 64 + tm * 16 + frow) * 64 + o * 8);
#pragma unroll
            for (int tn = 0; tn < 4; ++tn)
                bf[tn] = *reinterpret_cast<const bf16x8_t*>(
                    Bs + (wc * 64 + tn * 16 + frow) * 64 + o * 8);
#pragma unroll
            for (int tm = 0; tm < 4; ++tm)
#pragma unroll
                for (int tn = 0; tn < 4; ++tn)
                    acc[tm][tn] = __builtin_amdgcn_mfma_f32_16x16x32_bf16(
                        af[tm], bf[tn], acc[tm][tn], 0, 0, 0);
        }
        __syncthreads();
    }

    // epilogue: fold sq + diag INF into LDS transpose, float4 store + rmin
    float sn[4]; int jn[4], nc[4];
#pragma unroll
    for (int tn = 0; tn < 4; ++tn) {
        nc[tn] = wc * 64 + tn * 16 + (l & 15);
        jn[tn] = jb + nc[tn];
        sn[tn] = sq[jn[tn]];
    }
#pragma unroll 1
    for (int h = 0; h < 2; ++h) {
        __syncthreads();  // h=0: MFMA reads done; h=1: prior T reads done
        if (wr == h) {
#pragma unroll
            for (int tm = 0; tm < 4; ++tm) {
#pragma unroll
                for (int r = 0; r < 4; ++r) {
                    int rl = tm * 16 + fq * 4 + r;
                    int m = m0 + h * 64 + rl;
                    float smv = sq[m];
#pragma unroll
                    for (int tn = 0; tn < 4; ++tn) {
                        float val = smv + sn[tn] - 2.f * acc[tm][tn][r];
                        if (m == jn[tn]) val = INFINITY;
                        T[rl * 132 + nc[tn]] = val;
                    }
                }
            }
        }
        __syncthreads();
#pragma unroll
        for (int u = 0; u < 8; ++u) {
            int idx = u * 256 + tid;              // 0..2047
            int rl = idx >> 5, c4 = idx & 31;
            float4 v4 = *reinterpret_cast<const float4*>(T + rl * 132 + c4 * 4);
            int m = m0 + h * 64 + rl;
            *reinterpret_cast<float4*>(D + (size_t)m * CHSZ + n0 + c4 * 4) = v4;
            // per-(row, 64-col tile) min: reduce over the aligned 16-lane group
            float vm = fminf(fminf(v4.x, v4.y), fminf(v4.z, v4.w));
            vm = fminf(vm, __shfl_xor(vm, 1));
            vm = fminf(vm, __shfl_xor(vm, 2));
            vm = fminf(vm, __shfl_xor(vm, 4));
            vm = fminf(vm, __shfl_xor(vm, 8));
            if ((tid & 15) == 0)
                rmin[(size_t)m * 32 + (n0 >> 6) + (c4 >> 4)] = vm;
        }
    }
}

// ---------------------------------------------------------------- knn select (C=64, tile-pruned)
// One wave per point. Loads 32 tile-minima; tau = 20th-smallest tile-min is
// a VALID upper bound on the chunk's 20th distance (the 20 smallest tile
// minima are attained by >=20 distinct candidates). Only tiles with
// rmin <= min(tau, carried d19) are loaded. Insert logic = exact lex
// (d, idx) == jax.lax.top_k tie-break; filter uses <= so boundary ties pass.
__global__ __launch_bounds__(256) void knn_select_kernel(
    const float* __restrict__ D, const float* __restrict__ rmin,
    float* __restrict__ sd, int* __restrict__ si,
    int* __restrict__ nbrs, int chunk_base, int first, int last) {
    const int tid = threadIdx.x;
    const int w = tid >> 6, l = tid & 63;
    const int p = blockIdx.x * 4 + w;

    float dl = INFINITY; int il = 0x7fffffff;
    if (!first && l < KNN) { dl = sd[(size_t)p * KNN + l]; il = si[(size_t)p * KNN + l]; }
    float d19 = __shfl(dl, 19); int i19 = __shfl(il, 19);

    float rm = (l < 32) ? rmin[(size_t)p * 32 + l] : INFINITY;
    float tau = seed_tau(rm, l);
    float tf = fminf(tau, d19);

    unsigned long long tb = __ballot(rm <= tf);
    while (tb) {
        int t = __ffsll(tb) - 1;
        tb &= tb - 1;
        if (__shfl(rm, t) > tf) continue;      // tf may have tightened
        float val = D[(size_t)p * CHSZ + t * 64 + l];
        bool q = val <= tf;
        unsigned long long bal = __ballot(q);
        while (bal) {
            int ln = __ffsll(bal) - 1;
            bal &= bal - 1;
            float cv = __shfl(val, ln);
            int cj = chunk_base + t * 64 + ln;
            if (cv < d19 || (cv == d19 && cj < i19)) {
                bool cmp = (dl < cv) || (dl == cv && il < cj);
                unsigned long long cb = __ballot(cmp) & 0xFFFFFull;
                int r = __popcll(cb);
                float sdl = __shfl_up(dl, 1);
                int sil = __shfl_up(il, 1);
                if (l == r) { dl = cv; il = cj; }
                else if (l > r && l < KNN) { dl = sdl; il = sil; }
                d19 = __shfl(dl, 19); i19 = __shfl(il, 19);
                tf = fminf(tau, d19);
            }
        }
    }
    if (l < KNN) {
        sd[(size_t)p * KNN + l] = dl;
        si[(size_t)p * KNN + l] = il;
        if (last) nbrs[(size_t)p * KNN + l] = il;
    }
}

// ---------------------------------------------------------------- knn fused (C=3)
// One wave per point over all candidates (single-wave scan keeps the
// strongest global-20th filter; 2-wave split regressed — R9).
__global__ __launch_bounds__(256) void knn3_fused_kernel(
    const float* __restrict__ X, const float* __restrict__ sq,
    int* __restrict__ nbrs, int N) {
    const int tid = threadIdx.x;
    const int w = tid >> 6, l = tid & 63;
    const int p = blockIdx.x * 4 + w;
    const float x0 = X[(size_t)p * 3], x1 = X[(size_t)p * 3 + 1], x2 = X[(size_t)p * 3 + 2];
    const float sp = sq[p];
    float dl = INFINITY; int il = 0x7fffffff;
    float d19 = INFINITY; int i19 = 0x7fffffff;
    float tau = INFINITY, tf = INFINITY;

#pragma unroll 1
    for (int j0 = 0; j0 < N; j0 += 256) {
        const int jl = j0 + 4 * l;
        const float4* xr = reinterpret_cast<const float4*>(X + (size_t)jl * 3);
        float4 r0 = xr[0], r1 = xr[1], r2 = xr[2];
        float4 sj = *reinterpret_cast<const float4*>(sq + jl);
        float v0 = sp + sj.x - 2.f * (x0 * r0.x + x1 * r0.y + x2 * r0.z);
        float v1 = sp + sj.y - 2.f * (x0 * r0.w + x1 * r1.x + x2 * r1.y);
        float v2 = sp + sj.z - 2.f * (x0 * r1.z + x1 * r1.w + x2 * r2.x);
        float v3 = sp + sj.w - 2.f * (x0 * r2.y + x1 * r2.z + x2 * r2.w);
        if (jl + 0 == p) v0 = INFINITY;
        if (jl + 1 == p) v1 = INFINITY;
        if (jl + 2 == p) v2 = INFINITY;
        if (jl + 3 == p) v3 = INFINITY;
        if (j0 == 0) {
            float mv = fminf(fminf(v0, v1), fminf(v2, v3));
            tau = seed_tau(mv, l);
            tf = tau;
        }
        bool q0 = v0 <= tf, q1 = v1 <= tf, q2 = v2 <= tf, q3 = v3 <= tf;
        unsigned long long anyb = __ballot(q0 | q1 | q2 | q3);
        if (!anyb) continue;
#pragma unroll
        for (int qq = 0; qq < 4; ++qq) {
            float vq = (qq == 0) ? v0 : (qq == 1) ? v1 : (qq == 2) ? v2 : v3;
            unsigned long long bal = __ballot((qq == 0) ? q0 : (qq == 1) ? q1 : (qq == 2) ? q2 : q3);
            while (bal) {
                int ln = __ffsll((unsigned long long)bal) - 1;
                bal &= bal - 1;
                float cv = __shfl(vq, ln);
                int cj = j0 + 4 * ln + qq;
                if (cv < d19 || (cv == d19 && cj < i19)) {
                    bool cmp = (dl < cv) || (dl == cv && il < cj);
                    unsigned long long cb = __ballot(cmp) & 0xFFFFFull;
                    int r = __popcll(cb);
                    float sdl = __shfl_up(dl, 1);
                    int sil = __shfl_up(il, 1);
                    if (l == r) { dl = cv; il = cj; }
                    else if (l > r && l < KNN) { dl = sdl; il = sil; }
                    d19 = __shfl(dl, 19); i19 = __shfl(il, 19);
                    tf = fminf(tau, d19);
                }
            }
        }
    }
    if (l < KNN) nbrs[(size_t)p * KNN + l] = il;
}

// ---------------------------------------------------------------- edgeconv (factored, fp32 exact)
template<int C>
__global__ void prep_w_kernel(const float* __restrict__ w, const float* __restrict__ b,
                              float* __restrict__ WW, float* __restrict__ bb) {
    int t = blockIdx.x * blockDim.x + threadIdx.x;
    if (t < 128) bb[t] = (t < 64) ? b[t] : 0.f;
    if (t >= C * 128) return;
    int c = t >> 7, f = t & 127;
    WW[t] = (f < 64) ? (w[c * 64 + f] - w[(C + c) * 64 + f]) : w[(C + c) * 64 + (f - 64)];
}

template<int C, int ROWS>
__global__ __launch_bounds__(128) void ec_gemm_kernel(
    const float* __restrict__ x, const float* __restrict__ WW,
    const float* __restrict__ bb, float* __restrict__ AB, int N) {
    __shared__ float Ws[C * 128];
    __shared__ float xs[ROWS * C];
    const int tid = threadIdx.x;
    const int r0 = blockIdx.x * ROWS;
    for (int idx = tid; idx < C * 32; idx += 128)
        reinterpret_cast<float4*>(Ws)[idx] = reinterpret_cast<const float4*>(WW)[idx];
    for (int idx = tid; idx < ROWS * C / 4; idx += 128)
        reinterpret_cast<float4*>(xs)[idx] =
            reinterpret_cast<const float4*>(x + (size_t)r0 * C)[idx];
    __syncthreads();
    const float bias = bb[tid];
#pragma unroll 1
    for (int r = 0; r < ROWS; ++r) {
        float acc = bias;
#pragma unroll
        for (int c = 0; c < C; ++c) acc = fmaf(xs[r * C + c], Ws[c * 128 + tid], acc);
        AB[(size_t)(r0 + r) * 128 + tid] = acc;
    }
}

// out + folded concat-split: also emits the bf16 hi/lo slice of cat at col0.
__global__ __launch_bounds__(256) void ec_max_kernel(
    const float* __restrict__ AB, const int* __restrict__ nbrs,
    float* __restrict__ out,
    unsigned short* __restrict__ cat_hi, unsigned short* __restrict__ cat_lo,
    int col0, int N) {
    const int tid = threadIdx.x;
    const int w = tid >> 6, f = tid & 63;
    const int i = blockIdx.x * 4 + w;
    const float a = AB[(size_t)i * 128 + f];
    const int* nb = nbrs + (size_t)i * KNN;
    float m = -3.4e38f;
#pragma unroll
    for (int j = 0; j < KNN; ++j) {
        int n = nb[j];
        m = fmaxf(m, AB[(size_t)n * 128 + 64 + f]);
    }
    float v = fmaxf(a + m, 0.f);
    out[(size_t)i * 64 + f] = v;
    unsigned short h = f2bf(v);
    cat_hi[(size_t)i * 192 + col0 + f] = h;
    cat_lo[(size_t)i * 192 + col0 + f] = f2bf(v - bf2f(h));
}

// ---------------------------------------------------------------- weight split: BT[F][3K]
__global__ void prep_bsplit_kernel(const float* __restrict__ W, unsigned short* __restrict__ BT,
                                   int K, int F) {
    int t = blockIdx.x * 256 + threadIdx.x;
    int K3 = 3 * K;
    if (t >= F * K3) return;
    int n = t / K3, kp = t - n * K3;
    int seg = kp / K;
    int k = kp - seg * K;
    float v = W[(size_t)k * F + n];
    unsigned short h = f2bf(v);
    BT[t] = (seg == 1) ? f2bf(v - bf2f(h)) : h;
}

// ---------------------------------------------------------------- split-bf16 MFMA GEMM
template<int BM, int BN, int SPLIT>
__global__ __launch_bounds__(256) void mfma_gemm_kernel(
    const unsigned short* __restrict__ Ahi, const unsigned short* __restrict__ Alo,
    const unsigned short* __restrict__ BT, const float* __restrict__ bias,
    float* __restrict__ Cf, unsigned short* __restrict__ Chi, unsigned short* __restrict__ Clo,
    int M, int N, int K) {
    constexpr int WR = BM / 64, WC = BN / 64;
    static_assert(WR * WC == 4, "4 waves");
    __shared__ __align__(16) unsigned short As[BM * 64];
    __shared__ __align__(16) unsigned short Bs[BN * 64];
    const int tid = threadIdx.x;
    const int w = tid >> 6, l = tid & 63;
    const int wr = w % WR, wc = w / WR;
    const int m0 = blockIdx.y * BM, n0 = blockIdx.x * BN;
    const int K3 = 3 * K;

    f32x4_t acc[4][4];
#pragma unroll
    for (int a = 0; a < 4; ++a)
#pragma unroll
        for (int b = 0; b < 4; ++b) acc[a][b] = (f32x4_t){0.f, 0.f, 0.f, 0.f};

    const int lr = l >> 3;
    const int swz = ((l & 7) ^ lr) * 8;
    const int frow = l & 15;
    const int fq = l >> 4;
    const int fswz = l & 7;

    for (int kt = 0; kt < K3 / 64; ++kt) {
        const int kk = kt * 64;
        const unsigned short* srcA; int k0;
        if (kk < K)            { srcA = Ahi; k0 = kk; }
        else if (kk < 2 * K)   { srcA = Ahi; k0 = kk - K; }
        else                   { srcA = Alo; k0 = kk - 2 * K; }
#pragma unroll
        for (int t = 0; t < BM / 32; ++t) {
            int row = w * (BM / 4) + t * 8;
            gload_lds16(srcA + (size_t)(m0 + row + lr) * K + k0 + swz,
                        (void*)(As + row * 64));
        }
#pragma unroll
        for (int t = 0; t < BN / 32; ++t) {
            int row = w * (BN / 4) + t * 8;
            gload_lds16(BT + (size_t)(n0 + row + lr) * K3 + kk + swz,
                        (void*)(Bs + row * 64));
        }
        __syncthreads();
#pragma unroll
        for (int ks = 0; ks < 2; ++ks) {
            bf16x8_t af[4], bf[4];
            const int o = (ks * 4 + fq) ^ fswz;
#pragma unroll
            for (int tm = 0; tm < 4; ++tm) {
                int row = wr * 64 + tm * 16 + frow;
                af[tm] = *reinterpret_cast<const bf16x8_t*>(As + row * 64 + o * 8);
            }
#pragma unroll
            for (int tn = 0; tn < 4; ++tn) {
                int row = wc * 64 + tn * 16 + frow;
                bf[tn] = *reinterpret_cast<const bf16x8_t*>(Bs + row * 64 + o * 8);
            }
#pragma unroll
            for (int tm = 0; tm < 4; ++tm)
#pragma unroll
                for (int tn = 0; tn < 4; ++tn)
                    acc[tm][tn] = __builtin_amdgcn_mfma_f32_16x16x32_bf16(
                        af[tm], bf[tn], acc[tm][tn], 0, 0, 0);
        }
        __syncthreads();
    }

#pragma unroll
    for (int tn = 0; tn < 4; ++tn) {
        int col = n0 + wc * 64 + tn * 16 + (l & 15);
        float bv = bias[col];
#pragma unroll
        for (int tm = 0; tm < 4; ++tm) {
#pragma unroll
            for (int r = 0; r < 4; ++r) {
                int row = m0 + wr * 64 + tm * 16 + (l >> 4) * 4 + r;
                float v = fmaxf(acc[tm][tn][r] + bv, 0.f);
                if constexpr (SPLIT) {
                    unsigned short h = f2bf(v);
                    Chi[(size_t)row * N + col] = h;
                    Clo[(size_t)row * N + col] = f2bf(v - bf2f(h));
                } else {
                    Cf[(size_t)row * N + col] = v;
                }
            }
        }
    }
}

// ---------------------------------------------------------------- last layer + log_softmax
__global__ __launch_bounds__(256) void last_layer_kernel(
    const float* __restrict__ A, const float* __restrict__ W,
    const float* __restrict__ b, float* __restrict__ out, int N) {
    constexpr int KD = 128, NC = 13;
    __shared__ float ws[KD * NC];
    __shared__ float bs[NC];
    const int tid = threadIdx.x;
    for (int idx = tid; idx < KD * NC; idx += 256) ws[idx] = W[idx];
    if (tid < NC) bs[tid] = b[tid];
    __syncthreads();
    int r = blockIdx.x * 256 + tid;
    if (r >= N) return;
    float acc[NC];
#pragma unroll
    for (int f = 0; f < NC; ++f) acc[f] = bs[f];
    const float4* row = reinterpret_cast<const float4*>(A + (size_t)r * KD);
#pragma unroll 4
    for (int c4 = 0; c4 < KD / 4; ++c4) {
        float4 v = row[c4];
#pragma unroll
        for (int f = 0; f < NC; ++f) acc[f] += v.x * ws[(c4 * 4 + 0) * NC + f];
#pragma unroll
        for (int f = 0; f < NC; ++f) acc[f] += v.y * ws[(c4 * 4 + 1) * NC + f];
#pragma unroll
        for (int f = 0; f < NC; ++f) acc[f] += v.z * ws[(c4 * 4 + 2) * NC + f];
#pragma unroll
        for (int f = 0; f < NC; ++f) acc[f] += v.w * ws[(c4 * 4 + 3) * NC + f];
    }
    float m = acc[0];
#pragma unroll
    for (int f = 1; f < NC; ++f) m = fmaxf(m, acc[f]);
    float s = 0.f;
#pragma unroll
    for (int f = 0; f < NC; ++f) s += expf(acc[f] - m);
    float ls = logf(s);
#pragma unroll
    for (int f = 0; f < NC; ++f) out[(size_t)r * NC + f] = acc[f] - m - ls;
}

// ---------------------------------------------------------------- launch
extern "C" void kernel_launch(void* const* d_in, const int* in_sizes, int n_in,
                              void* d_out, int out_size, void* d_ws, size_t ws_size,
                              hipStream_t stream) {
    const float* x   = (const float*)d_in[0];
    const float* w1  = (const float*)d_in[1];
    const float* b1  = (const float*)d_in[2];
    const float* w2  = (const float*)d_in[3];
    const float* b2  = (const float*)d_in[4];
    const float* w3  = (const float*)d_in[5];
    const float* b3  = (const float*)d_in[6];
    const float* wl1 = (const float*)d_in[7];
    const float* bl1 = (const float*)d_in[8];
    const float* wm1 = (const float*)d_in[9];
    const float* bm1 = (const float*)d_in[10];
    const float* wm2 = (const float*)d_in[11];
    const float* bm2 = (const float*)d_in[12];
    const float* wm3 = (const float*)d_in[13];
    const float* bm3 = (const float*)d_in[14];
    float* out = (float*)d_out;

    const int N = in_sizes[0] / 3;  // 8192
    const int NCH = N / CHSZ;       // 4 chunks

    float* ws = (float*)d_ws;
    size_t off = 0;
    auto alloc = [&](size_t n) { float* p = ws + off; off += n; return p; };
    float* sq  = alloc(N);
    int*   nbr = (int*)alloc((size_t)N * KNN);
    float* x1  = alloc((size_t)N * 64);
    float* x2  = alloc((size_t)N * 64);
    float* x3  = alloc((size_t)N * 64);
    float* AB  = alloc((size_t)N * 128);
    float* WW  = alloc(64 * 128);
    float* bb  = alloc(128);
    float* sd  = alloc((size_t)N * KNN);
    int*   si  = (int*)alloc((size_t)N * KNN);
    float* rmin = alloc((size_t)N * 32);                                    // tile64 minima
    unsigned short* Xs = (unsigned short*)alloc((size_t)N * 192 / 2);       // triple-split [N][192]
    unsigned short* bt1 = (unsigned short*)alloc((size_t)1024 * 576 / 2);   // [1024][576]
    unsigned short* bt2 = (unsigned short*)alloc((size_t)256 * 3072 / 2);   // [256][3072]
    unsigned short* bt3 = (unsigned short*)alloc((size_t)128 * 768 / 2);    // [128][768]
    // cat lives OUTSIDE the D union (ec_max writes it before/while D is live)
    unsigned short* cat_hi = (unsigned short*)alloc((size_t)N * 192 / 2);
    unsigned short* cat_lo = (unsigned short*)alloc((size_t)N * 192 / 2);
    // union region: D chunk (knn phase) vs head activations (head phase)
    size_t dsz = (size_t)N * CHSZ;  // 16.8M floats > head usage (11.5M)
    float* Z = alloc(dsz);
    float* D = Z;
    unsigned short* a1_hi  = (unsigned short*)Z;
    unsigned short* a1_lo  = a1_hi + (size_t)N * 1024;
    unsigned short* a2_hi  = a1_lo + (size_t)N * 1024;
    unsigned short* a2_lo  = a2_hi + (size_t)N * 256;
    float* a3 = (float*)(a2_lo + (size_t)N * 256);

    // ---- stage 1 (C=3): fused dist+select, single dispatch
    rowsq_kernel<3><<<N / 256, 256, 0, stream>>>(x, sq, N);
    knn3_fused_kernel<<<N / 4, 256, 0, stream>>>(x, sq, nbr, N);
    prep_w_kernel<3><<<2, 256, 0, stream>>>(w1, b1, WW, bb);
    ec_gemm_kernel<3, 8><<<N / 8, 128, 0, stream>>>(x, WW, bb, AB, N);
    ec_max_kernel<<<N / 4, 256, 0, stream>>>(AB, nbr, x1, cat_hi, cat_lo, 0, N);
    // ---- stage 2 (C=64): MFMA distance + tile-min pruned select
    rowsq_kernel<64><<<N / 256, 256, 0, stream>>>(x1, sq, N);
    xsplit3_kernel<<<(N * 64 + 255) / 256, 256, 0, stream>>>(x1, Xs, N);
    for (int c = 0; c < NCH; ++c) {
        dist_mfma_kernel<<<dim3(CHSZ / 128, N / 128), 256, 0, stream>>>(Xs, sq, D, rmin, c * CHSZ);
        knn_select_kernel<<<N / 4, 256, 0, stream>>>(D, rmin, sd, si, nbr, c * CHSZ, c == 0, c == NCH - 1);
    }
    prep_w_kernel<64><<<32, 256, 0, stream>>>(w2, b2, WW, bb);
    ec_gemm_kernel<64, 8><<<N / 8, 128, 0, stream>>>(x1, WW, bb, AB, N);
    ec_max_kernel<<<N / 4, 256, 0, stream>>>(AB, nbr, x2, cat_hi, cat_lo, 64, N);
    // ---- stage 3 (C=64)
    rowsq_kernel<64><<<N / 256, 256, 0, stream>>>(x2, sq, N);
    xsplit3_kernel<<<(N * 64 + 255) / 256, 256, 0, stream>>>(x2, Xs, N);
    for (int c = 0; c < NCH; ++c) {
        dist_mfma_kernel<<<dim3(CHSZ / 128, N / 128), 256, 0, stream>>>(Xs, sq, D, rmin, c * CHSZ);
        knn_select_kernel<<<N / 4, 256, 0, stream>>>(D, rmin, sd, si, nbr, c * CHSZ, c == 0, c == NCH - 1);
    }
    prep_w_kernel<64><<<32, 256, 0, stream>>>(w3, b3, WW, bb);
    ec_gemm_kernel<64, 8><<<N / 8, 128, 0, stream>>>(x2, WW, bb, AB, N);
    ec_max_kernel<<<N / 4, 256, 0, stream>>>(AB, nbr, x3, cat_hi, cat_lo, 128, N);
    // ---- MLP head (split-bf16 MFMA)
    prep_bsplit_kernel<<<(1024 * 576 + 255) / 256, 256, 0, stream>>>(wl1, bt1, 192, 1024);
    prep_bsplit_kernel<<<(256 * 3072 + 255) / 256, 256, 0, stream>>>(wm1, bt2, 1024, 256);
    prep_bsplit_kernel<<<(128 * 768 + 255) / 256, 256, 0, stream>>>(wm2, bt3, 256, 128);
    mfma_gemm_kernel<128, 128, 1><<<dim3(1024 / 128, N / 128), 256, 0, stream>>>(
        cat_hi, cat_lo, bt1, bl1, nullptr, a1_hi, a1_lo, N, 1024, 192);
    mfma_gemm_kernel<256, 64, 1><<<dim3(256 / 64, N / 256), 256, 0, stream>>>(
        a1_hi, a1_lo, bt2, bm1, nullptr, a2_hi, a2_lo, N, 256, 1024);
    mfma_gemm_kernel<256, 64, 0><<<dim3(128 / 64, N / 256), 256, 0, stream>>>(
        a2_hi, a2_lo, bt3, bm2, a3, nullptr, nullptr, N, 128, 256);
    last_layer_kernel<<<(N + 255) / 256, 256, 0, stream>>>(a3, wm3, bm3, out, N);
}